// Round 4
// baseline (493.324 us; speedup 1.0000x reference)
//
#include <hip/hip_runtime.h>
#include <hip/hip_bf16.h>
#include <math.h>

// fragment types
typedef __attribute__((ext_vector_type(8))) short bfrag;    // 8 bf16
typedef __attribute__((ext_vector_type(4))) short short4v;  // 4 bf16
typedef __attribute__((ext_vector_type(4))) float f32x4;

#define LDK 136  // padded LDS row length in bf16 elems (272B rows, 16B-aligned)

// exact bf16(bits-in-short) -> f32
static __device__ __forceinline__ float b2f(short s)
{
    unsigned int u = ((unsigned int)(unsigned short)s) << 16;
    float f;
    __builtin_memcpy(&f, &u, 4);
    return f;
}

static __device__ __forceinline__ short4v pack4(f32x4 a)
{
    short4v o;
#pragma unroll
    for (int r = 0; r < 4; ++r) {
        __hip_bfloat16 h = __float2bfloat16(a[r]);
        short s;
        __builtin_memcpy(&s, &h, 2);
        o[r] = s;
    }
    return o;
}

static __device__ __forceinline__ bfrag pack8(f32x4 a, f32x4 b)
{
    bfrag o;
#pragma unroll
    for (int j = 0; j < 4; ++j) {
        __hip_bfloat16 h = __float2bfloat16(a[j]);
        short s;
        __builtin_memcpy(&s, &h, 2);
        o[j] = s;
    }
#pragma unroll
    for (int j = 0; j < 4; ++j) {
        __hip_bfloat16 h = __float2bfloat16(b[j]);
        short s;
        __builtin_memcpy(&s, &h, 2);
        o[4 + j] = s;
    }
    return o;
}

// ---------------------------------------------------------------------------
// Prep: W[128][128] fp32 -> bf16 transposed WT[n][k].  (unchanged, verified)
// Order in ws: 0=Wq 1=Wk 2=Wv 3=Wo 4=W1 5=W2 6=Wq_s 7=Wk_s
// ---------------------------------------------------------------------------
__global__ __launch_bounds__(256) void prep_weights(
    const float* __restrict__ Wq, const float* __restrict__ Wk,
    const float* __restrict__ Wv, const float* __restrict__ Wo,
    const float* __restrict__ W1, const float* __restrict__ W2,
    const float* __restrict__ Wqs, const float* __restrict__ Wks,
    __hip_bfloat16* __restrict__ out)
{
    __shared__ __hip_bfloat16 t[128 * 17];
    const float* Ws[8] = {Wq, Wk, Wv, Wo, W1, W2, Wqs, Wks};
    const int mat = blockIdx.x >> 3;
    const int slab = blockIdx.x & 7;
    const float* W = Ws[mat];
    const int n0 = slab * 16;
    __hip_bfloat16* o = out + (size_t)mat * 16384 + (size_t)n0 * 128;

#pragma unroll
    for (int p = 0; p < 2; ++p) {
        int idx = p * 256 + threadIdx.x;
        int k = idx >> 2, c4 = idx & 3;
        float4 f = *(const float4*)(W + k * 128 + n0 + c4 * 4);
        __hip_bfloat16* d = t + k * 17 + c4 * 4;
        d[0] = __float2bfloat16(f.x); d[1] = __float2bfloat16(f.y);
        d[2] = __float2bfloat16(f.z); d[3] = __float2bfloat16(f.w);
    }
    __syncthreads();
    {
        int n = threadIdx.x >> 4;
        int k0 = (threadIdx.x & 15) * 8;
        __hip_bfloat16 v[8];
#pragma unroll
        for (int j = 0; j < 8; ++j) v[j] = t[(k0 + j) * 17 + n];
        *(bfrag*)(o + n * 128 + k0) = *(const bfrag*)v;
    }
}

// ---------------------------------------------------------------------------
// One-wave 16x128 @ 128x128 matmuls. x[kk] = X[m][kk*32+quad*8 .. +8].
// mmT8: acc[ct][r] = OUT[m][ct*16+quad*4+r]       (col-group layout)
// mmR8: acc[ct][r] = OUT[quad*4+r][ct*16+m]       (row layout; V only)
// ---------------------------------------------------------------------------
__device__ __forceinline__ void mmT8(const bfrag x[4],
                                     const __hip_bfloat16* __restrict__ wT,
                                     int m, int quad, f32x4 acc[8])
{
    const f32x4 z = {0.f, 0.f, 0.f, 0.f};
#pragma unroll
    for (int ct = 0; ct < 8; ++ct) acc[ct] = z;
#pragma unroll
    for (int kk = 0; kk < 4; ++kk)
#pragma unroll
        for (int ct = 0; ct < 8; ++ct) {
            bfrag w = *(const bfrag*)(wT + (size_t)(ct * 16 + m) * 128 + kk * 32 + quad * 8);
            acc[ct] = __builtin_amdgcn_mfma_f32_16x16x32_bf16(w, x[kk], acc[ct], 0, 0, 0);
        }
}

__device__ __forceinline__ void mmR8(const bfrag x[4],
                                     const __hip_bfloat16* __restrict__ wT,
                                     int m, int quad, f32x4 acc[8])
{
    const f32x4 z = {0.f, 0.f, 0.f, 0.f};
#pragma unroll
    for (int ct = 0; ct < 8; ++ct) acc[ct] = z;
#pragma unroll
    for (int kk = 0; kk < 4; ++kk)
#pragma unroll
        for (int ct = 0; ct < 8; ++ct) {
            bfrag w = *(const bfrag*)(wT + (size_t)(ct * 16 + m) * 128 + kk * 32 + quad * 8);
            acc[ct] = __builtin_amdgcn_mfma_f32_16x16x32_bf16(x[kk], w, acc[ct], 0, 0, 0);
        }
}

// ---------------------------------------------------------------------------
// fused model: ONE WAVE PER BATCH. 64-thread blocks, zero __syncthreads.
// Register-pressure diet vs R3: long-lived KS / H-residual arrays live in
// per-lane LDS spill slots (intra-wave DS ordering, no barriers); S6 residual
// re-reads the selected city row from L1/L2 instead of holding it in VGPRs.
// ---------------------------------------------------------------------------
__global__ __launch_bounds__(64) void fused_model(
    const float* __restrict__ agent_embed,   // [B,16,128]
    const float* __restrict__ city_embed,    // [B,128,128]
    const int* __restrict__ acts,            // [B,16]
    const __hip_bfloat16* __restrict__ wts,  // 8 x WT[128][128] bf16
    const float* __restrict__ ln1g, const float* __restrict__ ln1b,
    const float* __restrict__ b1, const float* __restrict__ b2,
    const float* __restrict__ ln2g, const float* __restrict__ ln2b,
    float* __restrict__ out)                 // [B,16,16]
{
    __shared__ __align__(16) __hip_bfloat16 sb[16 * LDK];   // re-layout buffer
    __shared__ __align__(16) __hip_bfloat16 sKSsp[8 * 64 * 4];  // KS lane-spill
    __shared__ __align__(16) __hip_bfloat16 sHsp [8 * 64 * 4];  // H residual lane-spill

    const int lane = threadIdx.x & 63;
    const int m = lane & 15;
    const int quad = lane >> 4;
    const int b = blockIdx.x;

    // ---- masks: conflict(q=m, k'=quad*4+r) ----
    const int aq = acts[b * 16 + m];   // acts[q] for q = m (also the gather row)
    bool keep[4];
#pragma unroll
    for (int r = 0; r < 4; ++r) {
        int ak = __shfl(aq, quad * 4 + r, 16);  // acts[quad*4+r]
        keep[r] = (aq == 0) ? (quad * 4 + r == m) : (ak == aq);
    }

    // ---- inputs: agent row m (k-slice), selected city row (k-slice) ----
    const float* arow = agent_embed + ((size_t)b * 16 + m) * 128;
    const float* crow = city_embed + ((size_t)b * 128 + aq) * 128;
    bfrag xa[4], xsk[4];
#pragma unroll
    for (int kk = 0; kk < 4; ++kk) {
        f32x4 a0 = *(const f32x4*)(arow + kk * 32 + quad * 8);
        f32x4 a1 = *(const f32x4*)(arow + kk * 32 + quad * 8 + 4);
        xa[kk] = pack8(a0, a1);
        f32x4 c0 = *(const f32x4*)(crow + kk * 32 + quad * 8);
        f32x4 c1 = *(const f32x4*)(crow + kk * 32 + quad * 8 + 4);
        xsk[kk] = pack8(c0, c1);
    }

    f32x4 acc[8];
    short4v kf[8], vf[8], qf[8];

    // ---- S1: K = agent @ Wk   (col-group == 16x16x16 A-frag) ----
    mmT8(xa, wts + 1 * 16384, m, quad, acc);
#pragma unroll
    for (int ct = 0; ct < 8; ++ct) kf[ct] = pack4(acc[ct]);
    // ---- S2: V = agent @ Wv   (row layout == PV A-frag) ----
    mmR8(xa, wts + 2 * 16384, m, quad, acc);
#pragma unroll
    for (int ct = 0; ct < 8; ++ct) vf[ct] = pack4(acc[ct]);
    // ---- S3: KS = agent @ Wk_s -> LDS lane-spill (read back at S12) ----
    mmT8(xa, wts + 7 * 16384, m, quad, acc);
#pragma unroll
    for (int ct = 0; ct < 8; ++ct)
        *(short4v*)(sKSsp + (ct * 64 + lane) * 4) = pack4(acc[ct]);
    // ---- S4: Q = selected @ Wq ----
    mmT8(xsk, wts + 0 * 16384, m, quad, acc);
#pragma unroll
    for (int ct = 0; ct < 8; ++ct) qf[ct] = pack4(acc[ct]);

    // ---- S5: 8-head attention, all in registers ----
    // sc = mfma16(K,Q): sc[r] = S[q=m][k=quad*4+r]; P stays in A-frag layout;
    // o  = mfma16(V,P): o[r] = O[m][h*16+quad*4+r] (col-group) -> LDS re-layout.
    {
        const f32x4 z4 = {0.f, 0.f, 0.f, 0.f};
#pragma unroll
        for (int h = 0; h < 8; ++h) {
            f32x4 sc = __builtin_amdgcn_mfma_f32_16x16x16bf16_1k(kf[h], qf[h], z4, 0, 0, 0);
            float e[4], s = 0.f;
#pragma unroll
            for (int r = 0; r < 4; ++r) {
                // scores tiny (|s|<~1): softmax without max-sub is exact enough
                e[r] = keep[r] ? __expf(sc[r] * 0.25f) : 0.f;
                s += e[r];
            }
            s += __shfl_xor(s, 16, 64);
            s += __shfl_xor(s, 32, 64);
            float inv = __builtin_amdgcn_rcpf(s);
            f32x4 p;
#pragma unroll
            for (int r = 0; r < 4; ++r) p[r] = e[r] * inv;
            short4v pa = pack4(p);
            f32x4 o4 = __builtin_amdgcn_mfma_f32_16x16x16bf16_1k(vf[h], pa, z4, 0, 0, 0);
            *(short4v*)(sb + m * LDK + h * 16 + quad * 4) = pack4(o4);
        }
    }
    bfrag xo[4];
#pragma unroll
    for (int kk = 0; kk < 4; ++kk)
        xo[kk] = *(const bfrag*)(sb + m * LDK + kk * 32 + quad * 8);

    // ---- S6: Y = O @ Wo + selected (residual re-read from global, f32) ----
    mmT8(xo, wts + 3 * 16384, m, quad, acc);
#pragma unroll
    for (int ct = 0; ct < 8; ++ct) {
        f32x4 cres = *(const f32x4*)(crow + ct * 16 + quad * 4);
#pragma unroll
        for (int r = 0; r < 4; ++r) acc[ct][r] += cres[r];
    }

    // ---- S7: LN1 in registers -> H (bf16 col-group; spilled to LDS for S9) ----
    {
        float s = 0.f, s2 = 0.f;
#pragma unroll
        for (int ct = 0; ct < 8; ++ct)
#pragma unroll
            for (int r = 0; r < 4; ++r) { float v = acc[ct][r]; s += v; s2 += v * v; }
        s += __shfl_xor(s, 16, 64);  s += __shfl_xor(s, 32, 64);
        s2 += __shfl_xor(s2, 16, 64); s2 += __shfl_xor(s2, 32, 64);
        float mu = s * (1.f / 128.f);
        float var = s2 * (1.f / 128.f) - mu * mu;
        float rs = rsqrtf(var + 1e-5f);
#pragma unroll
        for (int ct = 0; ct < 8; ++ct) {
            f32x4 g4 = *(const f32x4*)(ln1g + ct * 16 + quad * 4);
            f32x4 bb4 = *(const f32x4*)(ln1b + ct * 16 + quad * 4);
            f32x4 hh;
#pragma unroll
            for (int r = 0; r < 4; ++r) hh[r] = (acc[ct][r] - mu) * rs * g4[r] + bb4[r];
            short4v hp = pack4(hh);
            *(short4v*)(sHsp + (ct * 64 + lane) * 4) = hp;          // residual spill
            *(short4v*)(sb + m * LDK + ct * 16 + quad * 4) = hp;    // re-layout
        }
    }
    bfrag hx[4];
#pragma unroll
    for (int kk = 0; kk < 4; ++kk)
        hx[kk] = *(const bfrag*)(sb + m * LDK + kk * 32 + quad * 8);

    // ---- S8: F1 = relu(H @ W1 + b1) ----
    mmT8(hx, wts + 4 * 16384, m, quad, acc);
#pragma unroll
    for (int ct = 0; ct < 8; ++ct) {
        f32x4 bb4 = *(const f32x4*)(b1 + ct * 16 + quad * 4);
        f32x4 f;
#pragma unroll
        for (int r = 0; r < 4; ++r) f[r] = fmaxf(acc[ct][r] + bb4[r], 0.f);
        *(short4v*)(sb + m * LDK + ct * 16 + quad * 4) = pack4(f);
    }
    bfrag fx[4];
#pragma unroll
    for (int kk = 0; kk < 4; ++kk)
        fx[kk] = *(const bfrag*)(sb + m * LDK + kk * 32 + quad * 8);

    // ---- S9: Z = H + F1 @ W2 + b2 (H residual from LDS spill) ----
    mmT8(fx, wts + 5 * 16384, m, quad, acc);
#pragma unroll
    for (int ct = 0; ct < 8; ++ct) {
        f32x4 bb4 = *(const f32x4*)(b2 + ct * 16 + quad * 4);
        short4v hv = *(const short4v*)(sHsp + (ct * 64 + lane) * 4);
#pragma unroll
        for (int r = 0; r < 4; ++r) acc[ct][r] += bb4[r] + b2f(hv[r]);
    }

    // ---- S10: LN2 in registers -> CAC ----
    {
        float s = 0.f, s2 = 0.f;
#pragma unroll
        for (int ct = 0; ct < 8; ++ct)
#pragma unroll
            for (int r = 0; r < 4; ++r) { float v = acc[ct][r]; s += v; s2 += v * v; }
        s += __shfl_xor(s, 16, 64);  s += __shfl_xor(s, 32, 64);
        s2 += __shfl_xor(s2, 16, 64); s2 += __shfl_xor(s2, 32, 64);
        float mu = s * (1.f / 128.f);
        float var = s2 * (1.f / 128.f) - mu * mu;
        float rs = rsqrtf(var + 1e-5f);
#pragma unroll
        for (int ct = 0; ct < 8; ++ct) {
            f32x4 g4 = *(const f32x4*)(ln2g + ct * 16 + quad * 4);
            f32x4 bb4 = *(const f32x4*)(ln2b + ct * 16 + quad * 4);
            f32x4 cc;
#pragma unroll
            for (int r = 0; r < 4; ++r) cc[r] = (acc[ct][r] - mu) * rs * g4[r] + bb4[r];
            *(short4v*)(sb + m * LDK + ct * 16 + quad * 4) = pack4(cc);
        }
    }
    bfrag cx[4];
#pragma unroll
    for (int kk = 0; kk < 4; ++kk)
        cx[kk] = *(const bfrag*)(sb + m * LDK + kk * 32 + quad * 8);

    // ---- S11: QS = CAC @ Wq_s ----
    mmT8(cx, wts + 6 * 16384, m, quad, acc);

    // ---- S12: logits = 10*tanh(QS @ KS^T / sqrt(128)), mask, store ----
    // la = sum_ct mfma16(KS,QS): la[r] = logits[q=m][k'=quad*4+r]
    {
        f32x4 la = {0.f, 0.f, 0.f, 0.f};
#pragma unroll
        for (int ct = 0; ct < 8; ++ct) {
            short4v ks4 = *(const short4v*)(sKSsp + (ct * 64 + lane) * 4);
            short4v qs4 = pack4(acc[ct]);
            la = __builtin_amdgcn_mfma_f32_16x16x16bf16_1k(ks4, qs4, la, 0, 0, 0);
        }
        f32x4 o4;
#pragma unroll
        for (int r = 0; r < 4; ++r) {
            float v = la[r] * 0.0883883476483184f;  // 1/sqrt(128)
            v = 10.f * tanhf(v);
            o4[r] = keep[r] ? v : -1e9f;
        }
        *(f32x4*)(out + ((size_t)b * 16 + m) * 16 + quad * 4) = o4;
    }
}

extern "C" void kernel_launch(void* const* d_in, const int* in_sizes, int n_in,
                              void* d_out, int out_size, void* d_ws, size_t ws_size,
                              hipStream_t stream)
{
    const float* agent = (const float*)d_in[0];
    const float* city  = (const float*)d_in[1];
    const int*   acts  = (const int*)d_in[2];
    const float* Wq  = (const float*)d_in[3];
    const float* Wk  = (const float*)d_in[4];
    const float* Wv  = (const float*)d_in[5];
    const float* Wo  = (const float*)d_in[6];
    const float* l1g = (const float*)d_in[7];
    const float* l1b = (const float*)d_in[8];
    const float* W1  = (const float*)d_in[9];
    const float* b1  = (const float*)d_in[10];
    const float* W2  = (const float*)d_in[11];
    const float* b2  = (const float*)d_in[12];
    const float* l2g = (const float*)d_in[13];
    const float* l2b = (const float*)d_in[14];
    const float* Wqs = (const float*)d_in[15];
    const float* Wks = (const float*)d_in[16];
    float* out = (float*)d_out;

    int B = in_sizes[2] / 16;  // acts is [B,16]
    __hip_bfloat16* wts = (__hip_bfloat16*)d_ws;  // 8*16384 bf16 = 256 KB

    prep_weights<<<64, 256, 0, stream>>>(Wq, Wk, Wv, Wo, W1, W2, Wqs, Wks, wts);
    fused_model<<<B, 64, 0, stream>>>(agent, city, acts, wts, l1g, l1b,
                                      b1, b2, l2g, l2b, out);
}

// Round 5
// 480.253 us; speedup vs baseline: 1.0272x; 1.0272x over previous
//
#include <hip/hip_runtime.h>
#include <hip/hip_bf16.h>
#include <math.h>

// fragment types
typedef __attribute__((ext_vector_type(8))) short bfrag;    // 8 bf16
typedef __attribute__((ext_vector_type(4))) short short4v;  // 4 bf16
typedef __attribute__((ext_vector_type(4))) float f32x4;

#define LDK 136  // padded LDS row length in bf16 elems (272B rows, 16B-aligned)

// exact bf16(bits-in-short) -> f32
static __device__ __forceinline__ float b2f(short s)
{
    unsigned int u = ((unsigned int)(unsigned short)s) << 16;
    float f;
    __builtin_memcpy(&f, &u, 4);
    return f;
}

static __device__ __forceinline__ short4v pack4(f32x4 a)
{
    short4v o;
#pragma unroll
    for (int r = 0; r < 4; ++r) {
        __hip_bfloat16 h = __float2bfloat16(a[r]);
        short s;
        __builtin_memcpy(&s, &h, 2);
        o[r] = s;
    }
    return o;
}

static __device__ __forceinline__ bfrag pack8(f32x4 a, f32x4 b)
{
    bfrag o;
#pragma unroll
    for (int j = 0; j < 4; ++j) {
        __hip_bfloat16 h = __float2bfloat16(a[j]);
        short s;
        __builtin_memcpy(&s, &h, 2);
        o[j] = s;
    }
#pragma unroll
    for (int j = 0; j < 4; ++j) {
        __hip_bfloat16 h = __float2bfloat16(b[j]);
        short s;
        __builtin_memcpy(&s, &h, 2);
        o[4 + j] = s;
    }
    return o;
}

// ---------------------------------------------------------------------------
// Prep: W[128][128] fp32 -> bf16 transposed WT[n][k].  (unchanged, verified)
// Order in ws: 0=Wq 1=Wk 2=Wv 3=Wo 4=W1 5=W2 6=Wq_s 7=Wk_s
// ---------------------------------------------------------------------------
__global__ __launch_bounds__(256) void prep_weights(
    const float* __restrict__ Wq, const float* __restrict__ Wk,
    const float* __restrict__ Wv, const float* __restrict__ Wo,
    const float* __restrict__ W1, const float* __restrict__ W2,
    const float* __restrict__ Wqs, const float* __restrict__ Wks,
    __hip_bfloat16* __restrict__ out)
{
    __shared__ __hip_bfloat16 t[128 * 17];
    const float* Ws[8] = {Wq, Wk, Wv, Wo, W1, W2, Wqs, Wks};
    const int mat = blockIdx.x >> 3;
    const int slab = blockIdx.x & 7;
    const float* W = Ws[mat];
    const int n0 = slab * 16;
    __hip_bfloat16* o = out + (size_t)mat * 16384 + (size_t)n0 * 128;

#pragma unroll
    for (int p = 0; p < 2; ++p) {
        int idx = p * 256 + threadIdx.x;
        int k = idx >> 2, c4 = idx & 3;
        float4 f = *(const float4*)(W + k * 128 + n0 + c4 * 4);
        __hip_bfloat16* d = t + k * 17 + c4 * 4;
        d[0] = __float2bfloat16(f.x); d[1] = __float2bfloat16(f.y);
        d[2] = __float2bfloat16(f.z); d[3] = __float2bfloat16(f.w);
    }
    __syncthreads();
    {
        int n = threadIdx.x >> 4;
        int k0 = (threadIdx.x & 15) * 8;
        __hip_bfloat16 v[8];
#pragma unroll
        for (int j = 0; j < 8; ++j) v[j] = t[(k0 + j) * 17 + n];
        *(bfrag*)(o + n * 128 + k0) = *(const bfrag*)v;
    }
}

// ---------------------------------------------------------------------------
// One-wave 16x128 @ 128x128 matmuls. x[kk] = X[m][kk*32+quad*8 .. +8].
// mmT8: acc[ct][r] = OUT[m][ct*16+quad*4+r]       (col-group layout)
// mmR8: acc[ct][r] = OUT[quad*4+r][ct*16+m]       (row layout; V only)
// ---------------------------------------------------------------------------
__device__ __forceinline__ void mmT8(const bfrag x[4],
                                     const __hip_bfloat16* __restrict__ wT,
                                     int m, int quad, f32x4 acc[8])
{
    const f32x4 z = {0.f, 0.f, 0.f, 0.f};
#pragma unroll
    for (int ct = 0; ct < 8; ++ct) acc[ct] = z;
#pragma unroll
    for (int kk = 0; kk < 4; ++kk)
#pragma unroll
        for (int ct = 0; ct < 8; ++ct) {
            bfrag w = *(const bfrag*)(wT + (size_t)(ct * 16 + m) * 128 + kk * 32 + quad * 8);
            acc[ct] = __builtin_amdgcn_mfma_f32_16x16x32_bf16(w, x[kk], acc[ct], 0, 0, 0);
        }
}

__device__ __forceinline__ void mmR8(const bfrag x[4],
                                     const __hip_bfloat16* __restrict__ wT,
                                     int m, int quad, f32x4 acc[8])
{
    const f32x4 z = {0.f, 0.f, 0.f, 0.f};
#pragma unroll
    for (int ct = 0; ct < 8; ++ct) acc[ct] = z;
#pragma unroll
    for (int kk = 0; kk < 4; ++kk)
#pragma unroll
        for (int ct = 0; ct < 8; ++ct) {
            bfrag w = *(const bfrag*)(wT + (size_t)(ct * 16 + m) * 128 + kk * 32 + quad * 8);
            acc[ct] = __builtin_amdgcn_mfma_f32_16x16x32_bf16(x[kk], w, acc[ct], 0, 0, 0);
        }
}

// ---------------------------------------------------------------------------
// fused model: 4 waves/block, ONE BATCH PER WAVE. No cross-wave data flow;
// __syncthreads() between stages only keeps waves time-converged so the
// current 32KB weight matrix is shared through L1. Datapath identical to the
// verified one-wave version; all state in registers (VGPR target <=128 via
// __launch_bounds__(256,4) -> 16 waves/CU).
// ---------------------------------------------------------------------------
__global__ __launch_bounds__(256, 4) void fused_model(
    const float* __restrict__ agent_embed,   // [B,16,128]
    const float* __restrict__ city_embed,    // [B,128,128]
    const int* __restrict__ acts,            // [B,16]
    const __hip_bfloat16* __restrict__ wts,  // 8 x WT[128][128] bf16
    const float* __restrict__ ln1g, const float* __restrict__ ln1b,
    const float* __restrict__ b1, const float* __restrict__ b2,
    const float* __restrict__ ln2g, const float* __restrict__ ln2b,
    float* __restrict__ out)                 // [B,16,16]
{
    __shared__ __align__(16) __hip_bfloat16 sbAll[4 * 16 * LDK];  // per-wave slices

    const int tid = threadIdx.x;
    const int wave = tid >> 6;
    const int lane = tid & 63;
    const int m = lane & 15;
    const int quad = lane >> 4;
    const int b = blockIdx.x * 4 + wave;
    __hip_bfloat16* const sb = sbAll + wave * (16 * LDK);

    // ---- masks: conflict(q=m, k'=quad*4+r) ----
    const int aq = acts[b * 16 + m];   // acts[q] for q = m (also the gather row)
    bool keep[4];
#pragma unroll
    for (int r = 0; r < 4; ++r) {
        int ak = __shfl(aq, quad * 4 + r, 16);  // acts[quad*4+r]
        keep[r] = (aq == 0) ? (quad * 4 + r == m) : (ak == aq);
    }

    // ---- inputs: agent row m (k-slice), selected city row (k-slice) ----
    const float* arow = agent_embed + ((size_t)b * 16 + m) * 128;
    const float* crow = city_embed + ((size_t)b * 128 + aq) * 128;
    bfrag xa[4], xsk[4];
#pragma unroll
    for (int kk = 0; kk < 4; ++kk) {
        f32x4 a0 = *(const f32x4*)(arow + kk * 32 + quad * 8);
        f32x4 a1 = *(const f32x4*)(arow + kk * 32 + quad * 8 + 4);
        xa[kk] = pack8(a0, a1);
        f32x4 c0 = *(const f32x4*)(crow + kk * 32 + quad * 8);
        f32x4 c1 = *(const f32x4*)(crow + kk * 32 + quad * 8 + 4);
        xsk[kk] = pack8(c0, c1);
    }

    f32x4 acc[8];
    short4v kf[8], vf[8], ksf[8], qf[8];

    // ---- S1: K = agent @ Wk   (col-group == 16x16x16 A-frag) ----
    mmT8(xa, wts + 1 * 16384, m, quad, acc);
#pragma unroll
    for (int ct = 0; ct < 8; ++ct) kf[ct] = pack4(acc[ct]);
    __syncthreads();
    // ---- S2: V = agent @ Wv   (row layout == PV A-frag) ----
    mmR8(xa, wts + 2 * 16384, m, quad, acc);
#pragma unroll
    for (int ct = 0; ct < 8; ++ct) vf[ct] = pack4(acc[ct]);
    __syncthreads();
    // ---- S3: KS = agent @ Wk_s (held in regs to S12) ----
    mmT8(xa, wts + 7 * 16384, m, quad, acc);
#pragma unroll
    for (int ct = 0; ct < 8; ++ct) ksf[ct] = pack4(acc[ct]);
    __syncthreads();
    // ---- S4: Q = selected @ Wq ----
    mmT8(xsk, wts + 0 * 16384, m, quad, acc);
#pragma unroll
    for (int ct = 0; ct < 8; ++ct) qf[ct] = pack4(acc[ct]);

    // ---- S5: 8-head attention, all in registers ----
    // sc = mfma16(K,Q): sc[r] = S[q=m][k=quad*4+r]; P stays in A-frag layout;
    // o  = mfma16(V,P): o[r] = O[m][h*16+quad*4+r] (col-group) -> LDS re-layout.
    {
        const f32x4 z4 = {0.f, 0.f, 0.f, 0.f};
#pragma unroll
        for (int h = 0; h < 8; ++h) {
            f32x4 sc = __builtin_amdgcn_mfma_f32_16x16x16bf16_1k(kf[h], qf[h], z4, 0, 0, 0);
            float e[4], s = 0.f;
#pragma unroll
            for (int r = 0; r < 4; ++r) {
                // scores tiny (|s|<~1): softmax without max-sub is exact enough
                e[r] = keep[r] ? __expf(sc[r] * 0.25f) : 0.f;
                s += e[r];
            }
            s += __shfl_xor(s, 16, 64);
            s += __shfl_xor(s, 32, 64);
            float inv = __builtin_amdgcn_rcpf(s);
            f32x4 p;
#pragma unroll
            for (int r = 0; r < 4; ++r) p[r] = e[r] * inv;
            short4v pa = pack4(p);
            f32x4 o4 = __builtin_amdgcn_mfma_f32_16x16x16bf16_1k(vf[h], pa, z4, 0, 0, 0);
            *(short4v*)(sb + m * LDK + h * 16 + quad * 4) = pack4(o4);
        }
    }
    bfrag xo[4];
#pragma unroll
    for (int kk = 0; kk < 4; ++kk)
        xo[kk] = *(const bfrag*)(sb + m * LDK + kk * 32 + quad * 8);
    __syncthreads();

    // ---- S6: Y = O @ Wo + selected (residual re-read from global, f32) ----
    mmT8(xo, wts + 3 * 16384, m, quad, acc);
#pragma unroll
    for (int ct = 0; ct < 8; ++ct) {
        f32x4 cres = *(const f32x4*)(crow + ct * 16 + quad * 4);
#pragma unroll
        for (int r = 0; r < 4; ++r) acc[ct][r] += cres[r];
    }

    // ---- S7: LN1 in registers -> H (bf16 col-group, kept for S9 residual) ----
    short4v hf[8];
    {
        float s = 0.f, s2 = 0.f;
#pragma unroll
        for (int ct = 0; ct < 8; ++ct)
#pragma unroll
            for (int r = 0; r < 4; ++r) { float v = acc[ct][r]; s += v; s2 += v * v; }
        s += __shfl_xor(s, 16, 64);  s += __shfl_xor(s, 32, 64);
        s2 += __shfl_xor(s2, 16, 64); s2 += __shfl_xor(s2, 32, 64);
        float mu = s * (1.f / 128.f);
        float var = s2 * (1.f / 128.f) - mu * mu;
        float rs = rsqrtf(var + 1e-5f);
#pragma unroll
        for (int ct = 0; ct < 8; ++ct) {
            f32x4 g4 = *(const f32x4*)(ln1g + ct * 16 + quad * 4);
            f32x4 bb4 = *(const f32x4*)(ln1b + ct * 16 + quad * 4);
            f32x4 hh;
#pragma unroll
            for (int r = 0; r < 4; ++r) hh[r] = (acc[ct][r] - mu) * rs * g4[r] + bb4[r];
            hf[ct] = pack4(hh);
            *(short4v*)(sb + m * LDK + ct * 16 + quad * 4) = hf[ct];
        }
    }
    bfrag hx[4];
#pragma unroll
    for (int kk = 0; kk < 4; ++kk)
        hx[kk] = *(const bfrag*)(sb + m * LDK + kk * 32 + quad * 8);
    __syncthreads();

    // ---- S8: F1 = relu(H @ W1 + b1) ----
    mmT8(hx, wts + 4 * 16384, m, quad, acc);
#pragma unroll
    for (int ct = 0; ct < 8; ++ct) {
        f32x4 bb4 = *(const f32x4*)(b1 + ct * 16 + quad * 4);
        f32x4 f;
#pragma unroll
        for (int r = 0; r < 4; ++r) f[r] = fmaxf(acc[ct][r] + bb4[r], 0.f);
        *(short4v*)(sb + m * LDK + ct * 16 + quad * 4) = pack4(f);
    }
    bfrag fx[4];
#pragma unroll
    for (int kk = 0; kk < 4; ++kk)
        fx[kk] = *(const bfrag*)(sb + m * LDK + kk * 32 + quad * 8);
    __syncthreads();

    // ---- S9: Z = H + F1 @ W2 + b2 ----
    mmT8(fx, wts + 5 * 16384, m, quad, acc);
#pragma unroll
    for (int ct = 0; ct < 8; ++ct) {
        f32x4 bb4 = *(const f32x4*)(b2 + ct * 16 + quad * 4);
#pragma unroll
        for (int r = 0; r < 4; ++r) acc[ct][r] += bb4[r] + b2f(hf[ct][r]);
    }

    // ---- S10: LN2 in registers -> CAC ----
    {
        float s = 0.f, s2 = 0.f;
#pragma unroll
        for (int ct = 0; ct < 8; ++ct)
#pragma unroll
            for (int r = 0; r < 4; ++r) { float v = acc[ct][r]; s += v; s2 += v * v; }
        s += __shfl_xor(s, 16, 64);  s += __shfl_xor(s, 32, 64);
        s2 += __shfl_xor(s2, 16, 64); s2 += __shfl_xor(s2, 32, 64);
        float mu = s * (1.f / 128.f);
        float var = s2 * (1.f / 128.f) - mu * mu;
        float rs = rsqrtf(var + 1e-5f);
#pragma unroll
        for (int ct = 0; ct < 8; ++ct) {
            f32x4 g4 = *(const f32x4*)(ln2g + ct * 16 + quad * 4);
            f32x4 bb4 = *(const f32x4*)(ln2b + ct * 16 + quad * 4);
            f32x4 cc;
#pragma unroll
            for (int r = 0; r < 4; ++r) cc[r] = (acc[ct][r] - mu) * rs * g4[r] + bb4[r];
            *(short4v*)(sb + m * LDK + ct * 16 + quad * 4) = pack4(cc);
        }
    }
    bfrag cx[4];
#pragma unroll
    for (int kk = 0; kk < 4; ++kk)
        cx[kk] = *(const bfrag*)(sb + m * LDK + kk * 32 + quad * 8);
    __syncthreads();

    // ---- S11: QS = CAC @ Wq_s ----
    mmT8(cx, wts + 6 * 16384, m, quad, acc);

    // ---- S12: logits = 10*tanh(QS @ KS^T / sqrt(128)), mask, store ----
    // la = sum_ct mfma16(KS,QS): la[r] = logits[q=m][k'=quad*4+r]
    {
        f32x4 la = {0.f, 0.f, 0.f, 0.f};
#pragma unroll
        for (int ct = 0; ct < 8; ++ct) {
            short4v qs4 = pack4(acc[ct]);
            la = __builtin_amdgcn_mfma_f32_16x16x16bf16_1k(ksf[ct], qs4, la, 0, 0, 0);
        }
        f32x4 o4;
#pragma unroll
        for (int r = 0; r < 4; ++r) {
            float v = la[r] * 0.0883883476483184f;  // 1/sqrt(128)
            v = 10.f * tanhf(v);
            o4[r] = keep[r] ? v : -1e9f;
        }
        *(f32x4*)(out + ((size_t)b * 16 + m) * 16 + quad * 4) = o4;
    }
}

extern "C" void kernel_launch(void* const* d_in, const int* in_sizes, int n_in,
                              void* d_out, int out_size, void* d_ws, size_t ws_size,
                              hipStream_t stream)
{
    const float* agent = (const float*)d_in[0];
    const float* city  = (const float*)d_in[1];
    const int*   acts  = (const int*)d_in[2];
    const float* Wq  = (const float*)d_in[3];
    const float* Wk  = (const float*)d_in[4];
    const float* Wv  = (const float*)d_in[5];
    const float* Wo  = (const float*)d_in[6];
    const float* l1g = (const float*)d_in[7];
    const float* l1b = (const float*)d_in[8];
    const float* W1  = (const float*)d_in[9];
    const float* b1  = (const float*)d_in[10];
    const float* W2  = (const float*)d_in[11];
    const float* b2  = (const float*)d_in[12];
    const float* l2g = (const float*)d_in[13];
    const float* l2b = (const float*)d_in[14];
    const float* Wqs = (const float*)d_in[15];
    const float* Wks = (const float*)d_in[16];
    float* out = (float*)d_out;

    int B = in_sizes[2] / 16;  // acts is [B,16]
    __hip_bfloat16* wts = (__hip_bfloat16*)d_ws;  // 8*16384 bf16 = 256 KB

    prep_weights<<<64, 256, 0, stream>>>(Wq, Wk, Wv, Wo, W1, W2, Wqs, Wks, wts);
    fused_model<<<B / 4, 256, 0, stream>>>(agent, city, acts, wts, l1g, l1b,
                                           b1, b2, l2g, l2b, out);
}

// Round 9
// 397.124 us; speedup vs baseline: 1.2422x; 1.2093x over previous
//
#include <hip/hip_runtime.h>
#include <hip/hip_bf16.h>
#include <math.h>

// fragment types
typedef __attribute__((ext_vector_type(8))) short bfrag;    // 8 bf16
typedef __attribute__((ext_vector_type(4))) short short4v;  // 4 bf16
typedef __attribute__((ext_vector_type(4))) float f32x4;

#define LDK 136  // padded LDS row length in bf16 elems (272B rows, 16B-aligned)

// exact bf16(bits-in-short) -> f32
static __device__ __forceinline__ float b2f(short s)
{
    unsigned int u = ((unsigned int)(unsigned short)s) << 16;
    float f;
    __builtin_memcpy(&f, &u, 4);
    return f;
}

static __device__ __forceinline__ short4v pack4(f32x4 a)
{
    short4v o;
#pragma unroll
    for (int r = 0; r < 4; ++r) {
        __hip_bfloat16 h = __float2bfloat16(a[r]);
        short s;
        __builtin_memcpy(&s, &h, 2);
        o[r] = s;
    }
    return o;
}

static __device__ __forceinline__ bfrag pack8(f32x4 a, f32x4 b)
{
    bfrag o;
#pragma unroll
    for (int j = 0; j < 4; ++j) {
        __hip_bfloat16 h = __float2bfloat16(a[j]);
        short s;
        __builtin_memcpy(&s, &h, 2);
        o[j] = s;
    }
#pragma unroll
    for (int j = 0; j < 4; ++j) {
        __hip_bfloat16 h = __float2bfloat16(b[j]);
        short s;
        __builtin_memcpy(&s, &h, 2);
        o[4 + j] = s;
    }
    return o;
}

// ---------------------------------------------------------------------------
// Prep: W[128][128] fp32 -> bf16, FRAGMENT-ORDERED for the fused kernel:
//   elem offset = mat*16384 + (ct*4+kk)*512 + lane*8 + j,  lane = quad*16+m,
//   holds WT[n=ct*16+m][k=kk*32+quad*8+j].
// Bucket = one (ct,kk) fragment set = 64 lanes x 8 bf16 = 512 elems
// (R7 BUG: used 1024-elem stride -> matrices overlapped + reader/stager
// disagreed -> NaN. 32 buckets x 512 = 16384 = one matrix. Fixed.)
// A wave's fragment load (all 64 lanes) is 1KB contiguous; linear LDS staging
// is conflict-free by construction (lane-consecutive 16B).
// Order in ws: 0=Wq 1=Wk 2=Wv 3=Wo 4=W1 5=W2 6=Wq_s 7=Wk_s
// ---------------------------------------------------------------------------
__global__ __launch_bounds__(256) void prep_weights(
    const float* __restrict__ Wq, const float* __restrict__ Wk,
    const float* __restrict__ Wv, const float* __restrict__ Wo,
    const float* __restrict__ W1, const float* __restrict__ W2,
    const float* __restrict__ Wqs, const float* __restrict__ Wks,
    __hip_bfloat16* __restrict__ out)
{
    __shared__ __hip_bfloat16 t[128 * 17];
    const float* Ws[8] = {Wq, Wk, Wv, Wo, W1, W2, Wqs, Wks};
    const int mat = blockIdx.x >> 3;
    const int slab = blockIdx.x & 7;   // = ct
    const float* W = Ws[mat];
    const int n0 = slab * 16;

#pragma unroll
    for (int p = 0; p < 2; ++p) {
        int idx = p * 256 + threadIdx.x;
        int k = idx >> 2, c4 = idx & 3;
        float4 f = *(const float4*)(W + k * 128 + n0 + c4 * 4);
        __hip_bfloat16* d = t + k * 17 + c4 * 4;
        d[0] = __float2bfloat16(f.x); d[1] = __float2bfloat16(f.y);
        d[2] = __float2bfloat16(f.z); d[3] = __float2bfloat16(f.w);
    }
    __syncthreads();
    {
        int m = threadIdx.x >> 4;          // 0..15 (row within ct-slab)
        int idx = threadIdx.x & 15;
        int k0 = idx * 8;                  // 0..120 = kk*32 + quad*8
        int kk = idx >> 2;                 // 0..3
        int quad = idx & 3;                // 0..3
        __hip_bfloat16 v[8];
#pragma unroll
        for (int j = 0; j < 8; ++j) v[j] = t[(k0 + j) * 17 + m];  // WT[n][k]=W[k][n]
        __hip_bfloat16* o = out + (size_t)mat * 16384
                          + (size_t)(slab * 4 + kk) * 512 + (quad * 16 + m) * 8;
        *(bfrag*)o = *(const bfrag*)v;
    }
}

// ---------------------------------------------------------------------------
// One-wave 16x128 @ 128x128 matmuls, weights from LDS (fragment-ordered).
// x[kk] = X[m][kk*32+quad*8 .. +8].
// mmT8: acc[ct][r] = OUT[m][ct*16+quad*4+r]       (col-group layout)
// mmR8: acc[ct][r] = OUT[quad*4+r][ct*16+m]       (row layout; V only)
// Fragment read: sW + (ct*4+kk)*512 + lane*8 -> lane-consecutive b128,
// conflict-free.
// ---------------------------------------------------------------------------
__device__ __forceinline__ void mmT8(const bfrag x[4],
                                     const __hip_bfloat16* sW,
                                     int lane, f32x4 acc[8])
{
    const f32x4 z = {0.f, 0.f, 0.f, 0.f};
#pragma unroll
    for (int ct = 0; ct < 8; ++ct) acc[ct] = z;
#pragma unroll
    for (int kk = 0; kk < 4; ++kk)
#pragma unroll
        for (int ct = 0; ct < 8; ++ct) {
            bfrag w = *(const bfrag*)(sW + (ct * 4 + kk) * 512 + lane * 8);
            acc[ct] = __builtin_amdgcn_mfma_f32_16x16x32_bf16(w, x[kk], acc[ct], 0, 0, 0);
        }
}

__device__ __forceinline__ void mmR8(const bfrag x[4],
                                     const __hip_bfloat16* sW,
                                     int lane, f32x4 acc[8])
{
    const f32x4 z = {0.f, 0.f, 0.f, 0.f};
#pragma unroll
    for (int ct = 0; ct < 8; ++ct) acc[ct] = z;
#pragma unroll
    for (int kk = 0; kk < 4; ++kk)
#pragma unroll
        for (int ct = 0; ct < 8; ++ct) {
            bfrag w = *(const bfrag*)(sW + (ct * 4 + kk) * 512 + lane * 8);
            acc[ct] = __builtin_amdgcn_mfma_f32_16x16x32_bf16(x[kk], w, acc[ct], 0, 0, 0);
        }
}

// ---------------------------------------------------------------------------
// fused model: 4 waves/block, ONE BATCH PER WAVE (datapath verified R4/R5).
// Per-stage weight matrix staged cooperatively into LDS (sW, 32KB) with
// async-split prefetch: issue next stage's 8x16B global loads BEFORE current
// compute (latency hides under MFMAs), commit to sW after the barrier.
// Weight L2 traffic: once per block per stage (was once per WAVE); inner-loop
// weight reads come from LDS, conflict-free.
// ---------------------------------------------------------------------------
__global__ __launch_bounds__(256) void fused_model(
    const float* __restrict__ agent_embed,   // [B,16,128]
    const float* __restrict__ city_embed,    // [B,128,128]
    const int* __restrict__ acts,            // [B,16]
    const __hip_bfloat16* __restrict__ wts,  // 8 x frag-ordered W, bf16
    const float* __restrict__ ln1g, const float* __restrict__ ln1b,
    const float* __restrict__ b1, const float* __restrict__ b2,
    const float* __restrict__ ln2g, const float* __restrict__ ln2b,
    float* __restrict__ out)                 // [B,16,16]
{
    __shared__ __align__(16) __hip_bfloat16 sW[16384];            // staged weights
    __shared__ __align__(16) __hip_bfloat16 sbAll[4 * 16 * LDK];  // per-wave slices

    const int tid = threadIdx.x;
    const int wave = tid >> 6;
    const int lane = tid & 63;
    const int m = lane & 15;
    const int quad = lane >> 4;
    const int b = blockIdx.x * 4 + wave;
    __hip_bfloat16* const sb = sbAll + wave * (16 * LDK);

    bfrag wreg[8];  // in-flight next-stage weights (prefetch window)

#define PRE(mat)                                                                \
    {                                                                           \
        const __hip_bfloat16* src = wts + (size_t)(mat) * 16384;                \
        _Pragma("unroll")                                                       \
        for (int i = 0; i < 8; ++i)                                             \
            wreg[i] = *(const bfrag*)(src + (i * 256 + tid) * 8);               \
    }
#define COMMIT()                                                                \
    {                                                                           \
        _Pragma("unroll")                                                       \
        for (int i = 0; i < 8; ++i)                                             \
            *(bfrag*)(sW + (i * 256 + tid) * 8) = wreg[i];                      \
    }

    // ---- masks: conflict(q=m, k'=quad*4+r) ----
    const int aq = acts[b * 16 + m];   // acts[q] for q = m (also the gather row)
    bool keep[4];
#pragma unroll
    for (int r = 0; r < 4; ++r) {
        int ak = __shfl(aq, quad * 4 + r, 16);  // acts[quad*4+r]
        keep[r] = (aq == 0) ? (quad * 4 + r == m) : (ak == aq);
    }

    // ---- prologue: stage Wk while loading inputs ----
    PRE(1);

    // ---- inputs: agent row m (k-slice), selected city row (k-slice) ----
    const float* arow = agent_embed + ((size_t)b * 16 + m) * 128;
    const float* crow = city_embed + ((size_t)b * 128 + aq) * 128;
    bfrag xa[4], xsk[4];
#pragma unroll
    for (int kk = 0; kk < 4; ++kk) {
        f32x4 a0 = *(const f32x4*)(arow + kk * 32 + quad * 8);
        f32x4 a1 = *(const f32x4*)(arow + kk * 32 + quad * 8 + 4);
        xa[kk] = pack8(a0, a1);
        f32x4 c0 = *(const f32x4*)(crow + kk * 32 + quad * 8);
        f32x4 c1 = *(const f32x4*)(crow + kk * 32 + quad * 8 + 4);
        xsk[kk] = pack8(c0, c1);
    }

    COMMIT();            // Wk -> sW
    __syncthreads();

    f32x4 acc[8];
    short4v kf[8], vf[8], ksf[8], qf[8];

    // ---- S1: K = agent @ Wk ----
    PRE(2);                                   // prefetch Wv under S1 compute
    mmT8(xa, sW, lane, acc);
#pragma unroll
    for (int ct = 0; ct < 8; ++ct) kf[ct] = pack4(acc[ct]);
    __syncthreads();
    COMMIT(); __syncthreads();                // Wv -> sW

    // ---- S2: V = agent @ Wv   (row layout == PV A-frag) ----
    PRE(7);                                   // prefetch Wk_s
    mmR8(xa, sW, lane, acc);
#pragma unroll
    for (int ct = 0; ct < 8; ++ct) vf[ct] = pack4(acc[ct]);
    __syncthreads();
    COMMIT(); __syncthreads();                // Wk_s -> sW

    // ---- S3: KS = agent @ Wk_s (held in regs to S12) ----
    PRE(0);                                   // prefetch Wq
    mmT8(xa, sW, lane, acc);
#pragma unroll
    for (int ct = 0; ct < 8; ++ct) ksf[ct] = pack4(acc[ct]);
    __syncthreads();
    COMMIT(); __syncthreads();                // Wq -> sW

    // ---- S4: Q = selected @ Wq ----
    PRE(3);                                   // prefetch Wo under S4+S5
    mmT8(xsk, sW, lane, acc);
#pragma unroll
    for (int ct = 0; ct < 8; ++ct) qf[ct] = pack4(acc[ct]);

    // ---- S5: 8-head attention, all in registers (no sW use) ----
    // sc = mfma16(K,Q): sc[r] = S[q=m][k=quad*4+r]; P stays in A-frag layout;
    // o  = mfma16(V,P): o[r] = O[m][h*16+quad*4+r] (col-group) -> sb re-layout.
    {
        const f32x4 z4 = {0.f, 0.f, 0.f, 0.f};
#pragma unroll
        for (int h = 0; h < 8; ++h) {
            f32x4 sc = __builtin_amdgcn_mfma_f32_16x16x16bf16_1k(kf[h], qf[h], z4, 0, 0, 0);
            float e[4], s = 0.f;
#pragma unroll
            for (int r = 0; r < 4; ++r) {
                // scores tiny (|s|<~1): softmax without max-sub is exact enough
                e[r] = keep[r] ? __expf(sc[r] * 0.25f) : 0.f;
                s += e[r];
            }
            s += __shfl_xor(s, 16, 64);
            s += __shfl_xor(s, 32, 64);
            float inv = __builtin_amdgcn_rcpf(s);
            f32x4 p;
#pragma unroll
            for (int r = 0; r < 4; ++r) p[r] = e[r] * inv;
            short4v pa = pack4(p);
            f32x4 o4 = __builtin_amdgcn_mfma_f32_16x16x16bf16_1k(vf[h], pa, z4, 0, 0, 0);
            *(short4v*)(sb + m * LDK + h * 16 + quad * 4) = pack4(o4);
        }
    }
    bfrag xo[4];
#pragma unroll
    for (int kk = 0; kk < 4; ++kk)
        xo[kk] = *(const bfrag*)(sb + m * LDK + kk * 32 + quad * 8);
    __syncthreads();
    COMMIT(); __syncthreads();                // Wo -> sW

    // ---- S6: Y = O @ Wo + selected (residual re-read from global, f32) ----
    PRE(4);                                   // prefetch W1 under S6+S7
    mmT8(xo, sW, lane, acc);
#pragma unroll
    for (int ct = 0; ct < 8; ++ct) {
        f32x4 cres = *(const f32x4*)(crow + ct * 16 + quad * 4);
#pragma unroll
        for (int r = 0; r < 4; ++r) acc[ct][r] += cres[r];
    }

    // ---- S7: LN1 in registers -> H (bf16 col-group, kept for S9 residual) ----
    short4v hf[8];
    {
        float s = 0.f, s2 = 0.f;
#pragma unroll
        for (int ct = 0; ct < 8; ++ct)
#pragma unroll
            for (int r = 0; r < 4; ++r) { float v = acc[ct][r]; s += v; s2 += v * v; }
        s += __shfl_xor(s, 16, 64);  s += __shfl_xor(s, 32, 64);
        s2 += __shfl_xor(s2, 16, 64); s2 += __shfl_xor(s2, 32, 64);
        float mu = s * (1.f / 128.f);
        float var = s2 * (1.f / 128.f) - mu * mu;
        float rs = rsqrtf(var + 1e-5f);
#pragma unroll
        for (int ct = 0; ct < 8; ++ct) {
            f32x4 g4 = *(const f32x4*)(ln1g + ct * 16 + quad * 4);
            f32x4 bb4 = *(const f32x4*)(ln1b + ct * 16 + quad * 4);
            f32x4 hh;
#pragma unroll
            for (int r = 0; r < 4; ++r) hh[r] = (acc[ct][r] - mu) * rs * g4[r] + bb4[r];
            hf[ct] = pack4(hh);
            *(short4v*)(sb + m * LDK + ct * 16 + quad * 4) = hf[ct];
        }
    }
    bfrag hx[4];
#pragma unroll
    for (int kk = 0; kk < 4; ++kk)
        hx[kk] = *(const bfrag*)(sb + m * LDK + kk * 32 + quad * 8);
    __syncthreads();
    COMMIT(); __syncthreads();                // W1 -> sW

    // ---- S8: F1 = relu(H @ W1 + b1) ----
    PRE(5);                                   // prefetch W2
    mmT8(hx, sW, lane, acc);
#pragma unroll
    for (int ct = 0; ct < 8; ++ct) {
        f32x4 bb4 = *(const f32x4*)(b1 + ct * 16 + quad * 4);
        f32x4 f;
#pragma unroll
        for (int r = 0; r < 4; ++r) f[r] = fmaxf(acc[ct][r] + bb4[r], 0.f);
        *(short4v*)(sb + m * LDK + ct * 16 + quad * 4) = pack4(f);
    }
    bfrag fx[4];
#pragma unroll
    for (int kk = 0; kk < 4; ++kk)
        fx[kk] = *(const bfrag*)(sb + m * LDK + kk * 32 + quad * 8);
    __syncthreads();
    COMMIT(); __syncthreads();                // W2 -> sW

    // ---- S9: Z = H + F1 @ W2 + b2 ----
    PRE(6);                                   // prefetch Wq_s under S9+S10
    mmT8(fx, sW, lane, acc);
#pragma unroll
    for (int ct = 0; ct < 8; ++ct) {
        f32x4 bb4 = *(const f32x4*)(b2 + ct * 16 + quad * 4);
#pragma unroll
        for (int r = 0; r < 4; ++r) acc[ct][r] += bb4[r] + b2f(hf[ct][r]);
    }

    // ---- S10: LN2 in registers -> CAC ----
    {
        float s = 0.f, s2 = 0.f;
#pragma unroll
        for (int ct = 0; ct < 8; ++ct)
#pragma unroll
            for (int r = 0; r < 4; ++r) { float v = acc[ct][r]; s += v; s2 += v * v; }
        s += __shfl_xor(s, 16, 64);  s += __shfl_xor(s, 32, 64);
        s2 += __shfl_xor(s2, 16, 64); s2 += __shfl_xor(s2, 32, 64);
        float mu = s * (1.f / 128.f);
        float var = s2 * (1.f / 128.f) - mu * mu;
        float rs = rsqrtf(var + 1e-5f);
#pragma unroll
        for (int ct = 0; ct < 8; ++ct) {
            f32x4 g4 = *(const f32x4*)(ln2g + ct * 16 + quad * 4);
            f32x4 bb4 = *(const f32x4*)(ln2b + ct * 16 + quad * 4);
            f32x4 cc;
#pragma unroll
            for (int r = 0; r < 4; ++r) cc[r] = (acc[ct][r] - mu) * rs * g4[r] + bb4[r];
            *(short4v*)(sb + m * LDK + ct * 16 + quad * 4) = pack4(cc);
        }
    }
    bfrag cx[4];
#pragma unroll
    for (int kk = 0; kk < 4; ++kk)
        cx[kk] = *(const bfrag*)(sb + m * LDK + kk * 32 + quad * 8);
    __syncthreads();
    COMMIT(); __syncthreads();                // Wq_s -> sW

    // ---- S11: QS = CAC @ Wq_s ----
    mmT8(cx, sW, lane, acc);

    // ---- S12: logits = 10*tanh(QS @ KS^T / sqrt(128)), mask, store ----
    // la = sum_ct mfma16(KS,QS): la[r] = logits[q=m][k'=quad*4+r]
    {
        f32x4 la = {0.f, 0.f, 0.f, 0.f};
#pragma unroll
        for (int ct = 0; ct < 8; ++ct) {
            short4v qs4 = pack4(acc[ct]);
            la = __builtin_amdgcn_mfma_f32_16x16x16bf16_1k(ksf[ct], qs4, la, 0, 0, 0);
        }
        f32x4 o4;
#pragma unroll
        for (int r = 0; r < 4; ++r) {
            float v = la[r] * 0.0883883476483184f;  // 1/sqrt(128)
            v = 10.f * tanhf(v);
            o4[r] = keep[r] ? v : -1e9f;
        }
        *(f32x4*)(out + ((size_t)b * 16 + m) * 16 + quad * 4) = o4;
    }
#undef PRE
#undef COMMIT
}

extern "C" void kernel_launch(void* const* d_in, const int* in_sizes, int n_in,
                              void* d_out, int out_size, void* d_ws, size_t ws_size,
                              hipStream_t stream)
{
    const float* agent = (const float*)d_in[0];
    const float* city  = (const float*)d_in[1];
    const int*   acts  = (const int*)d_in[2];
    const float* Wq  = (const float*)d_in[3];
    const float* Wk  = (const float*)d_in[4];
    const float* Wv  = (const float*)d_in[5];
    const float* Wo  = (const float*)d_in[6];
    const float* l1g = (const float*)d_in[7];
    const float* l1b = (const float*)d_in[8];
    const float* W1  = (const float*)d_in[9];
    const float* b1  = (const float*)d_in[10];
    const float* W2  = (const float*)d_in[11];
    const float* b2  = (const float*)d_in[12];
    const float* l2g = (const float*)d_in[13];
    const float* l2b = (const float*)d_in[14];
    const float* Wqs = (const float*)d_in[15];
    const float* Wks = (const float*)d_in[16];
    float* out = (float*)d_out;

    int B = in_sizes[2] / 16;  // acts is [B,16]
    __hip_bfloat16* wts = (__hip_bfloat16*)d_ws;  // 8*16384 bf16 = 256 KB

    prep_weights<<<64, 256, 0, stream>>>(Wq, Wk, Wv, Wo, W1, W2, Wqs, Wks, wts);
    fused_model<<<B / 4, 256, 0, stream>>>(agent, city, acts, wts, l1g, l1b,
                                           b1, b2, l2g, l2b, out);
}

// Round 12
// 395.365 us; speedup vs baseline: 1.2478x; 1.0045x over previous
//
#include <hip/hip_runtime.h>
#include <hip/hip_bf16.h>
#include <math.h>

// fragment types
typedef __attribute__((ext_vector_type(8))) short bfrag;    // 8 bf16
typedef __attribute__((ext_vector_type(4))) short short4v;  // 4 bf16
typedef __attribute__((ext_vector_type(4))) float f32x4;

#define LDK 136  // padded LDS row length in bf16 elems (272B rows, 16B-aligned)

// exact bf16(bits-in-short) -> f32
static __device__ __forceinline__ float b2f(short s)
{
    unsigned int u = ((unsigned int)(unsigned short)s) << 16;
    float f;
    __builtin_memcpy(&f, &u, 4);
    return f;
}

static __device__ __forceinline__ short4v pack4(f32x4 a)
{
    short4v o;
#pragma unroll
    for (int r = 0; r < 4; ++r) {
        __hip_bfloat16 h = __float2bfloat16(a[r]);
        short s;
        __builtin_memcpy(&s, &h, 2);
        o[r] = s;
    }
    return o;
}

static __device__ __forceinline__ bfrag pack8(f32x4 a, f32x4 b)
{
    bfrag o;
#pragma unroll
    for (int j = 0; j < 4; ++j) {
        __hip_bfloat16 h = __float2bfloat16(a[j]);
        short s;
        __builtin_memcpy(&s, &h, 2);
        o[j] = s;
    }
#pragma unroll
    for (int j = 0; j < 4; ++j) {
        __hip_bfloat16 h = __float2bfloat16(b[j]);
        short s;
        __builtin_memcpy(&s, &h, 2);
        o[4 + j] = s;
    }
    return o;
}

// ---------------------------------------------------------------------------
// Prep: W[128][128] fp32 -> bf16, FRAGMENT-ORDERED (verified R9):
//   elem offset = mat*16384 + (ct*4+kk)*512 + lane*8 + j,  lane = quad*16+m,
//   holds WT[n=ct*16+m][k=kk*32+quad*8+j].
// Order in ws: 0=Wq 1=Wk 2=Wv 3=Wo 4=W1 5=W2 6=Wq_s 7=Wk_s
// ---------------------------------------------------------------------------
__global__ __launch_bounds__(256) void prep_weights(
    const float* __restrict__ Wq, const float* __restrict__ Wk,
    const float* __restrict__ Wv, const float* __restrict__ Wo,
    const float* __restrict__ W1, const float* __restrict__ W2,
    const float* __restrict__ Wqs, const float* __restrict__ Wks,
    __hip_bfloat16* __restrict__ out)
{
    __shared__ __hip_bfloat16 t[128 * 17];
    const float* Ws[8] = {Wq, Wk, Wv, Wo, W1, W2, Wqs, Wks};
    const int mat = blockIdx.x >> 3;
    const int slab = blockIdx.x & 7;   // = ct
    const float* W = Ws[mat];
    const int n0 = slab * 16;

#pragma unroll
    for (int p = 0; p < 2; ++p) {
        int idx = p * 256 + threadIdx.x;
        int k = idx >> 2, c4 = idx & 3;
        float4 f = *(const float4*)(W + k * 128 + n0 + c4 * 4);
        __hip_bfloat16* d = t + k * 17 + c4 * 4;
        d[0] = __float2bfloat16(f.x); d[1] = __float2bfloat16(f.y);
        d[2] = __float2bfloat16(f.z); d[3] = __float2bfloat16(f.w);
    }
    __syncthreads();
    {
        int m = threadIdx.x >> 4;          // 0..15 (row within ct-slab)
        int idx = threadIdx.x & 15;
        int k0 = idx * 8;                  // 0..120 = kk*32 + quad*8
        int kk = idx >> 2;                 // 0..3
        int quad = idx & 3;                // 0..3
        __hip_bfloat16 v[8];
#pragma unroll
        for (int j = 0; j < 8; ++j) v[j] = t[(k0 + j) * 17 + m];  // WT[n][k]=W[k][n]
        __hip_bfloat16* o = out + (size_t)mat * 16384
                          + (size_t)(slab * 4 + kk) * 512 + (quad * 16 + m) * 8;
        *(bfrag*)o = *(const bfrag*)v;
    }
}

// ---------------------------------------------------------------------------
// One-wave 16x128 @ 128x128 matmuls, weights from LDS (fragment-ordered).
// x[kk] = X[m][kk*32+quad*8 .. +8].
// mmT8: acc[ct][r] = OUT[m][ct*16+quad*4+r]       (col-group layout)
// mmR8: acc[ct][r] = OUT[quad*4+r][ct*16+m]       (row layout; V only)
// Fragment read: sW + (ct*4+kk)*512 + lane*8 -> lane-consecutive b128,
// conflict-free.
// ---------------------------------------------------------------------------
__device__ __forceinline__ void mmT8(const bfrag x[4],
                                     const __hip_bfloat16* sW,
                                     int lane, f32x4 acc[8])
{
    const f32x4 z = {0.f, 0.f, 0.f, 0.f};
#pragma unroll
    for (int ct = 0; ct < 8; ++ct) acc[ct] = z;
#pragma unroll
    for (int kk = 0; kk < 4; ++kk)
#pragma unroll
        for (int ct = 0; ct < 8; ++ct) {
            bfrag w = *(const bfrag*)(sW + (ct * 4 + kk) * 512 + lane * 8);
            acc[ct] = __builtin_amdgcn_mfma_f32_16x16x32_bf16(w, x[kk], acc[ct], 0, 0, 0);
        }
}

__device__ __forceinline__ void mmR8(const bfrag x[4],
                                     const __hip_bfloat16* sW,
                                     int lane, f32x4 acc[8])
{
    const f32x4 z = {0.f, 0.f, 0.f, 0.f};
#pragma unroll
    for (int ct = 0; ct < 8; ++ct) acc[ct] = z;
#pragma unroll
    for (int kk = 0; kk < 4; ++kk)
#pragma unroll
        for (int ct = 0; ct < 8; ++ct) {
            bfrag w = *(const bfrag*)(sW + (ct * 4 + kk) * 512 + lane * 8);
            acc[ct] = __builtin_amdgcn_mfma_f32_16x16x32_bf16(x[kk], w, acc[ct], 0, 0, 0);
        }
}

// ---------------------------------------------------------------------------
// fused model: 8 waves/block (512 thr), ONE BATCH PER WAVE. vs R9 (4 waves):
// staging traffic + barrier count PER BATCH halve; grid = B/8 = 512 blocks =
// exactly 2 resident/CU (66KB LDS), 16 waves/CU. Residual xsr held in regs
// (captured while city row is L1-hot) - kills S6's 32MB global re-read.
// ---------------------------------------------------------------------------
__global__ __launch_bounds__(512) void fused_model(
    const float* __restrict__ agent_embed,   // [B,16,128]
    const float* __restrict__ city_embed,    // [B,128,128]
    const int* __restrict__ acts,            // [B,16]
    const __hip_bfloat16* __restrict__ wts,  // 8 x frag-ordered W, bf16
    const float* __restrict__ ln1g, const float* __restrict__ ln1b,
    const float* __restrict__ b1, const float* __restrict__ b2,
    const float* __restrict__ ln2g, const float* __restrict__ ln2b,
    float* __restrict__ out)                 // [B,16,16]
{
    __shared__ __align__(16) __hip_bfloat16 sW[16384];            // staged weights
    __shared__ __align__(16) __hip_bfloat16 sbAll[8 * 16 * LDK];  // per-wave slices

    const int tid = threadIdx.x;
    const int wave = tid >> 6;
    const int lane = tid & 63;
    const int m = lane & 15;
    const int quad = lane >> 4;
    const int b = blockIdx.x * 8 + wave;
    __hip_bfloat16* const sb = sbAll + wave * (16 * LDK);

    bfrag wreg[4];  // in-flight next-stage weights (prefetch window)

#define PRE(mat)                                                                \
    {                                                                           \
        const __hip_bfloat16* src = wts + (size_t)(mat) * 16384;                \
        _Pragma("unroll")                                                       \
        for (int i = 0; i < 4; ++i)                                             \
            wreg[i] = *(const bfrag*)(src + (i * 512 + tid) * 8);               \
    }
#define COMMIT()                                                                \
    {                                                                           \
        _Pragma("unroll")                                                       \
        for (int i = 0; i < 4; ++i)                                             \
            *(bfrag*)(sW + (i * 512 + tid) * 8) = wreg[i];                      \
    }

    // ---- masks: conflict(q=m, k'=quad*4+r) ----
    const int aq = acts[b * 16 + m];   // acts[q] for q = m (also the gather row)
    bool keep[4];
#pragma unroll
    for (int r = 0; r < 4; ++r) {
        int ak = __shfl(aq, quad * 4 + r, 16);  // acts[quad*4+r]
        keep[r] = (aq == 0) ? (quad * 4 + r == m) : (ak == aq);
    }

    // ---- prologue: stage Wk while loading inputs ----
    PRE(1);

    // ---- inputs: agent row m (k-slice), selected city row (k-slice + residual) ----
    const float* arow = agent_embed + ((size_t)b * 16 + m) * 128;
    const float* crow = city_embed + ((size_t)b * 128 + aq) * 128;
    bfrag xa[4], xsk[4];
#pragma unroll
    for (int kk = 0; kk < 4; ++kk) {
        f32x4 a0 = *(const f32x4*)(arow + kk * 32 + quad * 8);
        f32x4 a1 = *(const f32x4*)(arow + kk * 32 + quad * 8 + 4);
        xa[kk] = pack8(a0, a1);
        f32x4 c0 = *(const f32x4*)(crow + kk * 32 + quad * 8);
        f32x4 c1 = *(const f32x4*)(crow + kk * 32 + quad * 8 + 4);
        xsk[kk] = pack8(c0, c1);
    }
    short4v xsr[8];  // selected, col-group layout (residual at S6); L1-hot now
#pragma unroll
    for (int ct = 0; ct < 8; ++ct)
        xsr[ct] = pack4(*(const f32x4*)(crow + ct * 16 + quad * 4));

    COMMIT();            // Wk -> sW
    __syncthreads();

    f32x4 acc[8];
    short4v kf[8], vf[8], ksf[8], qf[8];

    // ---- S1: K = agent @ Wk ----
    PRE(2);                                   // prefetch Wv under S1 compute
    mmT8(xa, sW, lane, acc);
#pragma unroll
    for (int ct = 0; ct < 8; ++ct) kf[ct] = pack4(acc[ct]);
    __syncthreads();
    COMMIT(); __syncthreads();                // Wv -> sW

    // ---- S2: V = agent @ Wv   (row layout == PV A-frag) ----
    PRE(7);                                   // prefetch Wk_s
    mmR8(xa, sW, lane, acc);
#pragma unroll
    for (int ct = 0; ct < 8; ++ct) vf[ct] = pack4(acc[ct]);
    __syncthreads();
    COMMIT(); __syncthreads();                // Wk_s -> sW

    // ---- S3: KS = agent @ Wk_s (held in regs to S12) ----
    PRE(0);                                   // prefetch Wq
    mmT8(xa, sW, lane, acc);
#pragma unroll
    for (int ct = 0; ct < 8; ++ct) ksf[ct] = pack4(acc[ct]);
    __syncthreads();
    COMMIT(); __syncthreads();                // Wq -> sW

    // ---- S4: Q = selected @ Wq ----
    PRE(3);                                   // prefetch Wo under S4+S5
    mmT8(xsk, sW, lane, acc);
#pragma unroll
    for (int ct = 0; ct < 8; ++ct) qf[ct] = pack4(acc[ct]);

    // ---- S5: 8-head attention, all in registers (no sW use) ----
    // sc = mfma16(K,Q): sc[r] = S[q=m][k=quad*4+r]; P stays in A-frag layout;
    // o  = mfma16(V,P): o[r] = O[m][h*16+quad*4+r] (col-group) -> sb re-layout.
    {
        const f32x4 z4 = {0.f, 0.f, 0.f, 0.f};
#pragma unroll
        for (int h = 0; h < 8; ++h) {
            f32x4 sc = __builtin_amdgcn_mfma_f32_16x16x16bf16_1k(kf[h], qf[h], z4, 0, 0, 0);
            float e[4], s = 0.f;
#pragma unroll
            for (int r = 0; r < 4; ++r) {
                // scores tiny (|s|<~1): softmax without max-sub is exact enough
                e[r] = keep[r] ? __expf(sc[r] * 0.25f) : 0.f;
                s += e[r];
            }
            s += __shfl_xor(s, 16, 64);
            s += __shfl_xor(s, 32, 64);
            float inv = __builtin_amdgcn_rcpf(s);
            f32x4 p;
#pragma unroll
            for (int r = 0; r < 4; ++r) p[r] = e[r] * inv;
            short4v pa = pack4(p);
            f32x4 o4 = __builtin_amdgcn_mfma_f32_16x16x16bf16_1k(vf[h], pa, z4, 0, 0, 0);
            *(short4v*)(sb + m * LDK + h * 16 + quad * 4) = pack4(o4);
        }
    }
    bfrag xo[4];
#pragma unroll
    for (int kk = 0; kk < 4; ++kk)
        xo[kk] = *(const bfrag*)(sb + m * LDK + kk * 32 + quad * 8);
    __syncthreads();
    COMMIT(); __syncthreads();                // Wo -> sW

    // ---- S6: Y = O @ Wo + selected (residual from registers) ----
    PRE(4);                                   // prefetch W1 under S6+S7
    mmT8(xo, sW, lane, acc);
#pragma unroll
    for (int ct = 0; ct < 8; ++ct)
#pragma unroll
        for (int r = 0; r < 4; ++r) acc[ct][r] += b2f(xsr[ct][r]);

    // ---- S7: LN1 in registers -> H (bf16 col-group, kept for S9 residual) ----
    short4v hf[8];
    {
        float s = 0.f, s2 = 0.f;
#pragma unroll
        for (int ct = 0; ct < 8; ++ct)
#pragma unroll
            for (int r = 0; r < 4; ++r) { float v = acc[ct][r]; s += v; s2 += v * v; }
        s += __shfl_xor(s, 16, 64);  s += __shfl_xor(s, 32, 64);
        s2 += __shfl_xor(s2, 16, 64); s2 += __shfl_xor(s2, 32, 64);
        float mu = s * (1.f / 128.f);
        float var = s2 * (1.f / 128.f) - mu * mu;
        float rs = rsqrtf(var + 1e-5f);
#pragma unroll
        for (int ct = 0; ct < 8; ++ct) {
            f32x4 g4 = *(const f32x4*)(ln1g + ct * 16 + quad * 4);
            f32x4 bb4 = *(const f32x4*)(ln1b + ct * 16 + quad * 4);
            f32x4 hh;
#pragma unroll
            for (int r = 0; r < 4; ++r) hh[r] = (acc[ct][r] - mu) * rs * g4[r] + bb4[r];
            hf[ct] = pack4(hh);
            *(short4v*)(sb + m * LDK + ct * 16 + quad * 4) = hf[ct];
        }
    }
    bfrag hx[4];
#pragma unroll
    for (int kk = 0; kk < 4; ++kk)
        hx[kk] = *(const bfrag*)(sb + m * LDK + kk * 32 + quad * 8);
    __syncthreads();
    COMMIT(); __syncthreads();                // W1 -> sW

    // ---- S8: F1 = relu(H @ W1 + b1) ----
    PRE(5);                                   // prefetch W2
    mmT8(hx, sW, lane, acc);
#pragma unroll
    for (int ct = 0; ct < 8; ++ct) {
        f32x4 bb4 = *(const f32x4*)(b1 + ct * 16 + quad * 4);
        f32x4 f;
#pragma unroll
        for (int r = 0; r < 4; ++r) f[r] = fmaxf(acc[ct][r] + bb4[r], 0.f);
        *(short4v*)(sb + m * LDK + ct * 16 + quad * 4) = pack4(f);
    }
    bfrag fx[4];
#pragma unroll
    for (int kk = 0; kk < 4; ++kk)
        fx[kk] = *(const bfrag*)(sb + m * LDK + kk * 32 + quad * 8);
    __syncthreads();
    COMMIT(); __syncthreads();                // W2 -> sW

    // ---- S9: Z = H + F1 @ W2 + b2 ----
    PRE(6);                                   // prefetch Wq_s under S9+S10
    mmT8(fx, sW, lane, acc);
#pragma unroll
    for (int ct = 0; ct < 8; ++ct) {
        f32x4 bb4 = *(const f32x4*)(b2 + ct * 16 + quad * 4);
#pragma unroll
        for (int r = 0; r < 4; ++r) acc[ct][r] += bb4[r] + b2f(hf[ct][r]);
    }

    // ---- S10: LN2 in registers -> CAC ----
    {
        float s = 0.f, s2 = 0.f;
#pragma unroll
        for (int ct = 0; ct < 8; ++ct)
#pragma unroll
            for (int r = 0; r < 4; ++r) { float v = acc[ct][r]; s += v; s2 += v * v; }
        s += __shfl_xor(s, 16, 64);  s += __shfl_xor(s, 32, 64);
        s2 += __shfl_xor(s2, 16, 64); s2 += __shfl_xor(s2, 32, 64);
        float mu = s * (1.f / 128.f);
        float var = s2 * (1.f / 128.f) - mu * mu;
        float rs = rsqrtf(var + 1e-5f);
#pragma unroll
        for (int ct = 0; ct < 8; ++ct) {
            f32x4 g4 = *(const f32x4*)(ln2g + ct * 16 + quad * 4);
            f32x4 bb4 = *(const f32x4*)(ln2b + ct * 16 + quad * 4);
            f32x4 cc;
#pragma unroll
            for (int r = 0; r < 4; ++r) cc[r] = (acc[ct][r] - mu) * rs * g4[r] + bb4[r];
            *(short4v*)(sb + m * LDK + ct * 16 + quad * 4) = pack4(cc);
        }
    }
    bfrag cx[4];
#pragma unroll
    for (int kk = 0; kk < 4; ++kk)
        cx[kk] = *(const bfrag*)(sb + m * LDK + kk * 32 + quad * 8);
    __syncthreads();
    COMMIT(); __syncthreads();                // Wq_s -> sW

    // ---- S11: QS = CAC @ Wq_s ----
    mmT8(cx, sW, lane, acc);

    // ---- S12: logits = 10*tanh(QS @ KS^T / sqrt(128)), mask, store ----
    // la = sum_ct mfma16(KS,QS): la[r] = logits[q=m][k'=quad*4+r]
    {
        f32x4 la = {0.f, 0.f, 0.f, 0.f};
#pragma unroll
        for (int ct = 0; ct < 8; ++ct) {
            short4v qs4 = pack4(acc[ct]);
            la = __builtin_amdgcn_mfma_f32_16x16x16bf16_1k(ksf[ct], qs4, la, 0, 0, 0);
        }
        f32x4 o4;
#pragma unroll
        for (int r = 0; r < 4; ++r) {
            float v = la[r] * 0.0883883476483184f;  // 1/sqrt(128)
            v = 10.f * tanhf(v);
            o4[r] = keep[r] ? v : -1e9f;
        }
        *(f32x4*)(out + ((size_t)b * 16 + m) * 16 + quad * 4) = o4;
    }
#undef PRE
#undef COMMIT
}

extern "C" void kernel_launch(void* const* d_in, const int* in_sizes, int n_in,
                              void* d_out, int out_size, void* d_ws, size_t ws_size,
                              hipStream_t stream)
{
    const float* agent = (const float*)d_in[0];
    const float* city  = (const float*)d_in[1];
    const int*   acts  = (const int*)d_in[2];
    const float* Wq  = (const float*)d_in[3];
    const float* Wk  = (const float*)d_in[4];
    const float* Wv  = (const float*)d_in[5];
    const float* Wo  = (const float*)d_in[6];
    const float* l1g = (const float*)d_in[7];
    const float* l1b = (const float*)d_in[8];
    const float* W1  = (const float*)d_in[9];
    const float* b1  = (const float*)d_in[10];
    const float* W2  = (const float*)d_in[11];
    const float* b2  = (const float*)d_in[12];
    const float* l2g = (const float*)d_in[13];
    const float* l2b = (const float*)d_in[14];
    const float* Wqs = (const float*)d_in[15];
    const float* Wks = (const float*)d_in[16];
    float* out = (float*)d_out;

    int B = in_sizes[2] / 16;  // acts is [B,16]
    __hip_bfloat16* wts = (__hip_bfloat16*)d_ws;  // 8*16384 bf16 = 256 KB

    prep_weights<<<64, 256, 0, stream>>>(Wq, Wk, Wv, Wo, W1, W2, Wqs, Wks, wts);
    fused_model<<<B / 8, 512, 0, stream>>>(agent, city, acts, wts, l1g, l1b,
                                           b1, b2, l2g, l2b, out);
}

// Round 18
// 382.778 us; speedup vs baseline: 1.2888x; 1.0329x over previous
//
#include <hip/hip_runtime.h>
#include <hip/hip_bf16.h>
#include <math.h>

// fragment types
typedef __attribute__((ext_vector_type(8))) short bfrag;    // 8 bf16
typedef __attribute__((ext_vector_type(4))) short short4v;  // 4 bf16
typedef __attribute__((ext_vector_type(4))) float f32x4;

#define LDK 136  // padded LDS row length in bf16 elems (272B rows, 16B-aligned)

// exact bf16(bits-in-short) -> f32
static __device__ __forceinline__ float b2f(short s)
{
    unsigned int u = ((unsigned int)(unsigned short)s) << 16;
    float f;
    __builtin_memcpy(&f, &u, 4);
    return f;
}

static __device__ __forceinline__ short4v pack4(f32x4 a)
{
    short4v o;
#pragma unroll
    for (int r = 0; r < 4; ++r) {
        __hip_bfloat16 h = __float2bfloat16(a[r]);
        short s;
        __builtin_memcpy(&s, &h, 2);
        o[r] = s;
    }
    return o;
}

static __device__ __forceinline__ bfrag pack8(f32x4 a, f32x4 b)
{
    bfrag o;
#pragma unroll
    for (int j = 0; j < 4; ++j) {
        __hip_bfloat16 h = __float2bfloat16(a[j]);
        short s;
        __builtin_memcpy(&s, &h, 2);
        o[j] = s;
    }
#pragma unroll
    for (int j = 0; j < 4; ++j) {
        __hip_bfloat16 h = __float2bfloat16(b[j]);
        short s;
        __builtin_memcpy(&s, &h, 2);
        o[4 + j] = s;
    }
    return o;
}

// ---------------------------------------------------------------------------
// Prep: W[128][128] fp32 -> bf16, FRAGMENT-ORDERED (verified R9):
//   elem offset = mat*16384 + (ct*4+kk)*512 + lane*8 + j,  lane = quad*16+m,
//   holds WT[n=ct*16+m][k=kk*32+quad*8+j].
// Order in ws: 0=Wq 1=Wk 2=Wv 3=Wo 4=W1 5=W2 6=Wq_s 7=Wk_s
// ---------------------------------------------------------------------------
__global__ __launch_bounds__(256) void prep_weights(
    const float* __restrict__ Wq, const float* __restrict__ Wk,
    const float* __restrict__ Wv, const float* __restrict__ Wo,
    const float* __restrict__ W1, const float* __restrict__ W2,
    const float* __restrict__ Wqs, const float* __restrict__ Wks,
    __hip_bfloat16* __restrict__ out)
{
    __shared__ __hip_bfloat16 t[128 * 17];
    const float* Ws[8] = {Wq, Wk, Wv, Wo, W1, W2, Wqs, Wks};
    const int mat = blockIdx.x >> 3;
    const int slab = blockIdx.x & 7;   // = ct
    const float* W = Ws[mat];
    const int n0 = slab * 16;

#pragma unroll
    for (int p = 0; p < 2; ++p) {
        int idx = p * 256 + threadIdx.x;
        int k = idx >> 2, c4 = idx & 3;
        float4 f = *(const float4*)(W + k * 128 + n0 + c4 * 4);
        __hip_bfloat16* d = t + k * 17 + c4 * 4;
        d[0] = __float2bfloat16(f.x); d[1] = __float2bfloat16(f.y);
        d[2] = __float2bfloat16(f.z); d[3] = __float2bfloat16(f.w);
    }
    __syncthreads();
    {
        int m = threadIdx.x >> 4;          // 0..15 (row within ct-slab)
        int idx = threadIdx.x & 15;
        int k0 = idx * 8;                  // 0..120 = kk*32 + quad*8
        int kk = idx >> 2;                 // 0..3
        int quad = idx & 3;                // 0..3
        __hip_bfloat16 v[8];
#pragma unroll
        for (int j = 0; j < 8; ++j) v[j] = t[(k0 + j) * 17 + m];  // WT[n][k]=W[k][n]
        __hip_bfloat16* o = out + (size_t)mat * 16384
                          + (size_t)(slab * 4 + kk) * 512 + (quad * 16 + m) * 8;
        *(bfrag*)o = *(const bfrag*)v;
    }
}

// ---------------------------------------------------------------------------
// Dual-batch 16x128 @ 128x128 matmuls, weights from LDS (fragment-ordered).
// Weight fragment loaded ONCE per (ct,kk), used for BOTH batches' MFMAs:
// halves LDS weight bytes per batch, doubles ILP between barriers.
// mmT8x2: accg[ct][r] = OUTg[m][ct*16+quad*4+r]   (col-group, per batch g)
// mmR8x2: accg[ct][r] = OUTg[quad*4+r][ct*16+m]   (row layout; V only)
// ---------------------------------------------------------------------------
__device__ __forceinline__ void mmT8x2(const bfrag x0[4], const bfrag x1[4],
                                       const __hip_bfloat16* sW, int lane,
                                       f32x4 acc0[8], f32x4 acc1[8])
{
    const f32x4 z = {0.f, 0.f, 0.f, 0.f};
#pragma unroll
    for (int ct = 0; ct < 8; ++ct) { acc0[ct] = z; acc1[ct] = z; }
#pragma unroll
    for (int kk = 0; kk < 4; ++kk)
#pragma unroll
        for (int ct = 0; ct < 8; ++ct) {
            bfrag w = *(const bfrag*)(sW + (ct * 4 + kk) * 512 + lane * 8);
            acc0[ct] = __builtin_amdgcn_mfma_f32_16x16x32_bf16(w, x0[kk], acc0[ct], 0, 0, 0);
            acc1[ct] = __builtin_amdgcn_mfma_f32_16x16x32_bf16(w, x1[kk], acc1[ct], 0, 0, 0);
        }
}

__device__ __forceinline__ void mmR8x2(const bfrag x0[4], const bfrag x1[4],
                                       const __hip_bfloat16* sW, int lane,
                                       f32x4 acc0[8], f32x4 acc1[8])
{
    const f32x4 z = {0.f, 0.f, 0.f, 0.f};
#pragma unroll
    for (int ct = 0; ct < 8; ++ct) { acc0[ct] = z; acc1[ct] = z; }
#pragma unroll
    for (int kk = 0; kk < 4; ++kk)
#pragma unroll
        for (int ct = 0; ct < 8; ++ct) {
            bfrag w = *(const bfrag*)(sW + (ct * 4 + kk) * 512 + lane * 8);
            acc0[ct] = __builtin_amdgcn_mfma_f32_16x16x32_bf16(x0[kk], w, acc0[ct], 0, 0, 0);
            acc1[ct] = __builtin_amdgcn_mfma_f32_16x16x32_bf16(x1[kk], w, acc1[ct], 0, 0, 0);
        }
}

// ---------------------------------------------------------------------------
// fused model: 4 waves/block (256 thr), TWO BATCHES PER WAVE (8/block).
// vs R12: each weight fragment read from LDS once serves 2 batches ->
// per-batch LDS weight traffic halves (the ~22us floor at R12's structure);
// 64 independent MFMAs between barrier pairs (2x ILP). 2 blocks/CU so
// barrier waits can slide between independent blocks. Layouts unchanged.
// ---------------------------------------------------------------------------
__global__ __launch_bounds__(256, 2) void fused_model(
    const float* __restrict__ agent_embed,   // [B,16,128]
    const float* __restrict__ city_embed,    // [B,128,128]
    const int* __restrict__ acts,            // [B,16]
    const __hip_bfloat16* __restrict__ wts,  // 8 x frag-ordered W, bf16
    const float* __restrict__ ln1g, const float* __restrict__ ln1b,
    const float* __restrict__ b1, const float* __restrict__ b2,
    const float* __restrict__ ln2g, const float* __restrict__ ln2b,
    float* __restrict__ out)                 // [B,16,16]
{
    __shared__ __align__(16) __hip_bfloat16 sW[16384];            // staged weights
    __shared__ __align__(16) __hip_bfloat16 sbAll[4 * 32 * LDK];  // per-wave 2-batch

    const int tid = threadIdx.x;
    const int wave = tid >> 6;
    const int lane = tid & 63;
    const int m = lane & 15;
    const int quad = lane >> 4;
    const int p0 = blockIdx.x * 8 + wave * 2;   // batch pair (p0, p0+1)
    const int p1 = p0 + 1;
    __hip_bfloat16* const sb0 = sbAll + wave * (32 * LDK);
    __hip_bfloat16* const sb1 = sb0 + 16 * LDK;

    bfrag wreg[8];  // in-flight next-stage weights (prefetch window)

#define PRE(mat)                                                                \
    {                                                                           \
        const __hip_bfloat16* src = wts + (size_t)(mat) * 16384;                \
        _Pragma("unroll")                                                       \
        for (int i = 0; i < 8; ++i)                                             \
            wreg[i] = *(const bfrag*)(src + (i * 256 + tid) * 8);               \
    }
#define COMMIT()                                                                \
    {                                                                           \
        _Pragma("unroll")                                                       \
        for (int i = 0; i < 8; ++i)                                             \
            *(bfrag*)(sW + (i * 256 + tid) * 8) = wreg[i];                      \
    }

    // ---- masks per batch: conflict(q=m, k'=quad*4+r) ----
    const int aq0 = acts[p0 * 16 + m];
    const int aq1 = acts[p1 * 16 + m];
    bool keep0[4], keep1[4];
#pragma unroll
    for (int r = 0; r < 4; ++r) {
        int ak0 = __shfl(aq0, quad * 4 + r, 16);
        int ak1 = __shfl(aq1, quad * 4 + r, 16);
        keep0[r] = (aq0 == 0) ? (quad * 4 + r == m) : (ak0 == aq0);
        keep1[r] = (aq1 == 0) ? (quad * 4 + r == m) : (ak1 == aq1);
    }

    // ---- prologue: stage Wk while loading inputs ----
    PRE(1);

    const float* arow0 = agent_embed + ((size_t)p0 * 16 + m) * 128;
    const float* arow1 = agent_embed + ((size_t)p1 * 16 + m) * 128;
    const float* crow0 = city_embed + ((size_t)p0 * 128 + aq0) * 128;
    const float* crow1 = city_embed + ((size_t)p1 * 128 + aq1) * 128;
    bfrag xa0[4], xa1[4], xsk0[4], xsk1[4];
#pragma unroll
    for (int kk = 0; kk < 4; ++kk) {
        xa0[kk] = pack8(*(const f32x4*)(arow0 + kk * 32 + quad * 8),
                        *(const f32x4*)(arow0 + kk * 32 + quad * 8 + 4));
        xa1[kk] = pack8(*(const f32x4*)(arow1 + kk * 32 + quad * 8),
                        *(const f32x4*)(arow1 + kk * 32 + quad * 8 + 4));
        xsk0[kk] = pack8(*(const f32x4*)(crow0 + kk * 32 + quad * 8),
                         *(const f32x4*)(crow0 + kk * 32 + quad * 8 + 4));
        xsk1[kk] = pack8(*(const f32x4*)(crow1 + kk * 32 + quad * 8),
                         *(const f32x4*)(crow1 + kk * 32 + quad * 8 + 4));
    }

    COMMIT();            // Wk -> sW
    __syncthreads();

    f32x4 acc0[8], acc1[8];
    short4v kf0[8], kf1[8], vf0[8], vf1[8], ksf0[8], ksf1[8], qf0[8], qf1[8];

    // ---- S1: K = agent @ Wk ----
    PRE(2);                                   // prefetch Wv under S1 compute
    mmT8x2(xa0, xa1, sW, lane, acc0, acc1);
#pragma unroll
    for (int ct = 0; ct < 8; ++ct) { kf0[ct] = pack4(acc0[ct]); kf1[ct] = pack4(acc1[ct]); }
    __syncthreads();
    COMMIT(); __syncthreads();                // Wv -> sW

    // ---- S2: V = agent @ Wv   (row layout == PV A-frag) ----
    PRE(7);                                   // prefetch Wk_s
    mmR8x2(xa0, xa1, sW, lane, acc0, acc1);
#pragma unroll
    for (int ct = 0; ct < 8; ++ct) { vf0[ct] = pack4(acc0[ct]); vf1[ct] = pack4(acc1[ct]); }
    __syncthreads();
    COMMIT(); __syncthreads();                // Wk_s -> sW

    // ---- S3: KS = agent @ Wk_s (held in regs to S12) ----
    PRE(0);                                   // prefetch Wq
    mmT8x2(xa0, xa1, sW, lane, acc0, acc1);
#pragma unroll
    for (int ct = 0; ct < 8; ++ct) { ksf0[ct] = pack4(acc0[ct]); ksf1[ct] = pack4(acc1[ct]); }
    __syncthreads();
    COMMIT(); __syncthreads();                // Wq -> sW

    // ---- S4: Q = selected @ Wq ----
    PRE(3);                                   // prefetch Wo under S4+S5
    mmT8x2(xsk0, xsk1, sW, lane, acc0, acc1);
#pragma unroll
    for (int ct = 0; ct < 8; ++ct) { qf0[ct] = pack4(acc0[ct]); qf1[ct] = pack4(acc1[ct]); }

    // ---- S5: 8-head attention, all in registers, per batch ----
    {
        const f32x4 z4 = {0.f, 0.f, 0.f, 0.f};
#pragma unroll
        for (int h = 0; h < 8; ++h) {
            // batch 0
            {
                f32x4 sc = __builtin_amdgcn_mfma_f32_16x16x16bf16_1k(kf0[h], qf0[h], z4, 0, 0, 0);
                float e[4], s = 0.f;
#pragma unroll
                for (int r = 0; r < 4; ++r) {
                    e[r] = keep0[r] ? __expf(sc[r] * 0.25f) : 0.f;
                    s += e[r];
                }
                s += __shfl_xor(s, 16, 64);
                s += __shfl_xor(s, 32, 64);
                float inv = __builtin_amdgcn_rcpf(s);
                f32x4 p;
#pragma unroll
                for (int r = 0; r < 4; ++r) p[r] = e[r] * inv;
                f32x4 o4 = __builtin_amdgcn_mfma_f32_16x16x16bf16_1k(vf0[h], pack4(p), z4, 0, 0, 0);
                *(short4v*)(sb0 + m * LDK + h * 16 + quad * 4) = pack4(o4);
            }
            // batch 1
            {
                f32x4 sc = __builtin_amdgcn_mfma_f32_16x16x16bf16_1k(kf1[h], qf1[h], z4, 0, 0, 0);
                float e[4], s = 0.f;
#pragma unroll
                for (int r = 0; r < 4; ++r) {
                    e[r] = keep1[r] ? __expf(sc[r] * 0.25f) : 0.f;
                    s += e[r];
                }
                s += __shfl_xor(s, 16, 64);
                s += __shfl_xor(s, 32, 64);
                float inv = __builtin_amdgcn_rcpf(s);
                f32x4 p;
#pragma unroll
                for (int r = 0; r < 4; ++r) p[r] = e[r] * inv;
                f32x4 o4 = __builtin_amdgcn_mfma_f32_16x16x16bf16_1k(vf1[h], pack4(p), z4, 0, 0, 0);
                *(short4v*)(sb1 + m * LDK + h * 16 + quad * 4) = pack4(o4);
            }
        }
    }
    bfrag xo0[4], xo1[4];
#pragma unroll
    for (int kk = 0; kk < 4; ++kk) {
        xo0[kk] = *(const bfrag*)(sb0 + m * LDK + kk * 32 + quad * 8);
        xo1[kk] = *(const bfrag*)(sb1 + m * LDK + kk * 32 + quad * 8);
    }
    __syncthreads();
    COMMIT(); __syncthreads();                // Wo -> sW

    // ---- S6: Y = O @ Wo + selected (residual re-read, L2-hot) ----
    PRE(4);                                   // prefetch W1 under S6+S7
    mmT8x2(xo0, xo1, sW, lane, acc0, acc1);
#pragma unroll
    for (int ct = 0; ct < 8; ++ct) {
        f32x4 c0 = *(const f32x4*)(crow0 + ct * 16 + quad * 4);
        f32x4 c1 = *(const f32x4*)(crow1 + ct * 16 + quad * 4);
#pragma unroll
        for (int r = 0; r < 4; ++r) { acc0[ct][r] += c0[r]; acc1[ct][r] += c1[r]; }
    }

    // ---- S7: LN1 -> H (regs + sb for re-layout), per batch ----
    short4v hf0[8], hf1[8];
    {
        float s0 = 0.f, s20 = 0.f, s1 = 0.f, s21 = 0.f;
#pragma unroll
        for (int ct = 0; ct < 8; ++ct)
#pragma unroll
            for (int r = 0; r < 4; ++r) {
                float v0 = acc0[ct][r]; s0 += v0; s20 += v0 * v0;
                float v1 = acc1[ct][r]; s1 += v1; s21 += v1 * v1;
            }
        s0 += __shfl_xor(s0, 16, 64);  s0 += __shfl_xor(s0, 32, 64);
        s20 += __shfl_xor(s20, 16, 64); s20 += __shfl_xor(s20, 32, 64);
        s1 += __shfl_xor(s1, 16, 64);  s1 += __shfl_xor(s1, 32, 64);
        s21 += __shfl_xor(s21, 16, 64); s21 += __shfl_xor(s21, 32, 64);
        float mu0 = s0 * (1.f / 128.f), mu1 = s1 * (1.f / 128.f);
        float rs0 = rsqrtf(s20 * (1.f / 128.f) - mu0 * mu0 + 1e-5f);
        float rs1 = rsqrtf(s21 * (1.f / 128.f) - mu1 * mu1 + 1e-5f);
#pragma unroll
        for (int ct = 0; ct < 8; ++ct) {
            f32x4 g4 = *(const f32x4*)(ln1g + ct * 16 + quad * 4);
            f32x4 bb4 = *(const f32x4*)(ln1b + ct * 16 + quad * 4);
            f32x4 h0, h1;
#pragma unroll
            for (int r = 0; r < 4; ++r) {
                h0[r] = (acc0[ct][r] - mu0) * rs0 * g4[r] + bb4[r];
                h1[r] = (acc1[ct][r] - mu1) * rs1 * g4[r] + bb4[r];
            }
            hf0[ct] = pack4(h0); hf1[ct] = pack4(h1);
            *(short4v*)(sb0 + m * LDK + ct * 16 + quad * 4) = hf0[ct];
            *(short4v*)(sb1 + m * LDK + ct * 16 + quad * 4) = hf1[ct];
        }
    }
    bfrag hx0[4], hx1[4];
#pragma unroll
    for (int kk = 0; kk < 4; ++kk) {
        hx0[kk] = *(const bfrag*)(sb0 + m * LDK + kk * 32 + quad * 8);
        hx1[kk] = *(const bfrag*)(sb1 + m * LDK + kk * 32 + quad * 8);
    }
    __syncthreads();
    COMMIT(); __syncthreads();                // W1 -> sW

    // ---- S8: F1 = relu(H @ W1 + b1) ----
    PRE(5);                                   // prefetch W2
    mmT8x2(hx0, hx1, sW, lane, acc0, acc1);
#pragma unroll
    for (int ct = 0; ct < 8; ++ct) {
        f32x4 bb4 = *(const f32x4*)(b1 + ct * 16 + quad * 4);
        f32x4 f0, f1;
#pragma unroll
        for (int r = 0; r < 4; ++r) {
            f0[r] = fmaxf(acc0[ct][r] + bb4[r], 0.f);
            f1[r] = fmaxf(acc1[ct][r] + bb4[r], 0.f);
        }
        *(short4v*)(sb0 + m * LDK + ct * 16 + quad * 4) = pack4(f0);
        *(short4v*)(sb1 + m * LDK + ct * 16 + quad * 4) = pack4(f1);
    }
    bfrag fx0[4], fx1[4];
#pragma unroll
    for (int kk = 0; kk < 4; ++kk) {
        fx0[kk] = *(const bfrag*)(sb0 + m * LDK + kk * 32 + quad * 8);
        fx1[kk] = *(const bfrag*)(sb1 + m * LDK + kk * 32 + quad * 8);
    }
    __syncthreads();
    COMMIT(); __syncthreads();                // W2 -> sW

    // ---- S9: Z = H + F1 @ W2 + b2 ----
    PRE(6);                                   // prefetch Wq_s under S9+S10
    mmT8x2(fx0, fx1, sW, lane, acc0, acc1);
#pragma unroll
    for (int ct = 0; ct < 8; ++ct) {
        f32x4 bb4 = *(const f32x4*)(b2 + ct * 16 + quad * 4);
#pragma unroll
        for (int r = 0; r < 4; ++r) {
            acc0[ct][r] += bb4[r] + b2f(hf0[ct][r]);
            acc1[ct][r] += bb4[r] + b2f(hf1[ct][r]);
        }
    }

    // ---- S10: LN2 -> CAC (sb), per batch ----
    {
        float s0 = 0.f, s20 = 0.f, s1 = 0.f, s21 = 0.f;
#pragma unroll
        for (int ct = 0; ct < 8; ++ct)
#pragma unroll
            for (int r = 0; r < 4; ++r) {
                float v0 = acc0[ct][r]; s0 += v0; s20 += v0 * v0;
                float v1 = acc1[ct][r]; s1 += v1; s21 += v1 * v1;
            }
        s0 += __shfl_xor(s0, 16, 64);  s0 += __shfl_xor(s0, 32, 64);
        s20 += __shfl_xor(s20, 16, 64); s20 += __shfl_xor(s20, 32, 64);
        s1 += __shfl_xor(s1, 16, 64);  s1 += __shfl_xor(s1, 32, 64);
        s21 += __shfl_xor(s21, 16, 64); s21 += __shfl_xor(s21, 32, 64);
        float mu0 = s0 * (1.f / 128.f), mu1 = s1 * (1.f / 128.f);
        float rs0 = rsqrtf(s20 * (1.f / 128.f) - mu0 * mu0 + 1e-5f);
        float rs1 = rsqrtf(s21 * (1.f / 128.f) - mu1 * mu1 + 1e-5f);
#pragma unroll
        for (int ct = 0; ct < 8; ++ct) {
            f32x4 g4 = *(const f32x4*)(ln2g + ct * 16 + quad * 4);
            f32x4 bb4 = *(const f32x4*)(ln2b + ct * 16 + quad * 4);
            f32x4 c0, c1;
#pragma unroll
            for (int r = 0; r < 4; ++r) {
                c0[r] = (acc0[ct][r] - mu0) * rs0 * g4[r] + bb4[r];
                c1[r] = (acc1[ct][r] - mu1) * rs1 * g4[r] + bb4[r];
            }
            *(short4v*)(sb0 + m * LDK + ct * 16 + quad * 4) = pack4(c0);
            *(short4v*)(sb1 + m * LDK + ct * 16 + quad * 4) = pack4(c1);
        }
    }
    bfrag cx0[4], cx1[4];
#pragma unroll
    for (int kk = 0; kk < 4; ++kk) {
        cx0[kk] = *(const bfrag*)(sb0 + m * LDK + kk * 32 + quad * 8);
        cx1[kk] = *(const bfrag*)(sb1 + m * LDK + kk * 32 + quad * 8);
    }
    __syncthreads();
    COMMIT(); __syncthreads();                // Wq_s -> sW

    // ---- S11: QS = CAC @ Wq_s ----
    mmT8x2(cx0, cx1, sW, lane, acc0, acc1);

    // ---- S12: logits = 10*tanh(QS @ KS^T / sqrt(128)), mask, store ----
    {
        f32x4 la0 = {0.f, 0.f, 0.f, 0.f};
        f32x4 la1 = {0.f, 0.f, 0.f, 0.f};
#pragma unroll
        for (int ct = 0; ct < 8; ++ct) {
            la0 = __builtin_amdgcn_mfma_f32_16x16x16bf16_1k(ksf0[ct], pack4(acc0[ct]), la0, 0, 0, 0);
            la1 = __builtin_amdgcn_mfma_f32_16x16x16bf16_1k(ksf1[ct], pack4(acc1[ct]), la1, 0, 0, 0);
        }
        f32x4 o0, o1;
#pragma unroll
        for (int r = 0; r < 4; ++r) {
            float v0 = 10.f * tanhf(la0[r] * 0.0883883476483184f);
            float v1 = 10.f * tanhf(la1[r] * 0.0883883476483184f);
            o0[r] = keep0[r] ? v0 : -1e9f;
            o1[r] = keep1[r] ? v1 : -1e9f;
        }
        *(f32x4*)(out + ((size_t)p0 * 16 + m) * 16 + quad * 4) = o0;
        *(f32x4*)(out + ((size_t)p1 * 16 + m) * 16 + quad * 4) = o1;
    }
#undef PRE
#undef COMMIT
}

extern "C" void kernel_launch(void* const* d_in, const int* in_sizes, int n_in,
                              void* d_out, int out_size, void* d_ws, size_t ws_size,
                              hipStream_t stream)
{
    const float* agent = (const float*)d_in[0];
    const float* city  = (const float*)d_in[1];
    const int*   acts  = (const int*)d_in[2];
    const float* Wq  = (const float*)d_in[3];
    const float* Wk  = (const float*)d_in[4];
    const float* Wv  = (const float*)d_in[5];
    const float* Wo  = (const float*)d_in[6];
    const float* l1g = (const float*)d_in[7];
    const float* l1b = (const float*)d_in[8];
    const float* W1  = (const float*)d_in[9];
    const float* b1  = (const float*)d_in[10];
    const float* W2  = (const float*)d_in[11];
    const float* b2  = (const float*)d_in[12];
    const float* l2g = (const float*)d_in[13];
    const float* l2b = (const float*)d_in[14];
    const float* Wqs = (const float*)d_in[15];
    const float* Wks = (const float*)d_in[16];
    float* out = (float*)d_out;

    int B = in_sizes[2] / 16;  // acts is [B,16]
    __hip_bfloat16* wts = (__hip_bfloat16*)d_ws;  // 8*16384 bf16 = 256 KB

    prep_weights<<<64, 256, 0, stream>>>(Wq, Wk, Wv, Wo, W1, W2, Wqs, Wks, wts);
    fused_model<<<B / 8, 256, 0, stream>>>(agent, city, acts, wts, l1g, l1b,
                                           b1, b2, l2g, l2b, out);
}